// Round 13
// baseline (701.594 us; speedup 1.0000x reference)
//
#include <hip/hip_runtime.h>
#include <hip/hip_bf16.h>

#define CDIM 128
#define NG 128
typedef unsigned int uint32;
typedef unsigned short ushort16;
typedef __attribute__((ext_vector_type(8))) short short8;
typedef __attribute__((ext_vector_type(4))) float floatx4;

__device__ __forceinline__ ushort16 f2bf(float f){
  uint32 u = __float_as_uint(f);
  u = (u + 0x7fffu + ((u >> 16) & 1u)) >> 16;   // RNE
  return (ushort16)u;
}

// ================= CSR build (unified graph: mg nodes [0,NM), pg nodes [NM,NT)) =================
__global__ void k_count_f(const int* __restrict__ dstM, const int* __restrict__ dstP,
                          int* __restrict__ deg, int EM, int ET, int NM){
  int e = blockIdx.x*blockDim.x + threadIdx.x;
  if (e < ET){
    int d = (e < EM) ? dstM[e] : dstP[e-EM] + NM;
    atomicAdd(&deg[d], 1);
  }
}

__global__ void k_scan1(const int* __restrict__ deg, int* __restrict__ rowptr,
                        int* __restrict__ sums, int N){
  __shared__ int tmp[1024];
  int b = blockIdx.x, t = threadIdx.x;
  int i = b*1024 + t;
  int v = (i < N) ? deg[i] : 0;
  tmp[t] = v; __syncthreads();
  for (int off = 1; off < 1024; off <<= 1){
    int a = (t >= off) ? tmp[t-off] : 0;
    __syncthreads();
    tmp[t] += a;
    __syncthreads();
  }
  if (i < N) rowptr[i] = tmp[t] - v;
  if (t == 1023) sums[b] = tmp[t];
}

__global__ void k_scan2(int* __restrict__ sums, int nb){
  __shared__ int tmp[1024];
  __shared__ int carry;
  int t = threadIdx.x;
  if (t == 0) carry = 0;
  __syncthreads();
  for (int base = 0; base < nb; base += 1024){
    int i = base + t;
    int v = (i < nb) ? sums[i] : 0;
    tmp[t] = v; __syncthreads();
    for (int off = 1; off < 1024; off <<= 1){
      int a = (t >= off) ? tmp[t-off] : 0;
      __syncthreads();
      tmp[t] += a;
      __syncthreads();
    }
    if (i < nb) sums[i] = carry + tmp[t] - v;
    int tot = tmp[1023];
    __syncthreads();
    if (t == 0) carry += tot;
    __syncthreads();
  }
  if (t == 0) sums[nb] = carry;
}

__global__ void k_scan3(int* __restrict__ rowptr, int* __restrict__ cursor,
                        const int* __restrict__ sums, int N, int nb){
  int i = blockIdx.x*blockDim.x + threadIdx.x;
  if (i < N){
    int r = rowptr[i] + sums[i >> 10];
    rowptr[i] = r; cursor[i] = r;
  }
  if (i == 0) rowptr[N] = sums[nb];
}

__global__ void k_scatter_f(const int* __restrict__ srcM, const int* __restrict__ srcP,
                            const int* __restrict__ dstM, const int* __restrict__ dstP,
                            int* __restrict__ cursor, int* __restrict__ csr_src,
                            int* __restrict__ csr_eid, int EM, int ET, int NM){
  int e = blockIdx.x*blockDim.x + threadIdx.x;
  if (e < ET){
    int s, d;
    if (e < EM){ s = srcM[e]; d = dstM[e]; }
    else       { s = srcP[e-EM] + NM; d = dstP[e-EM] + NM; }
    int pos = atomicAdd(&cursor[d], 1);
    csr_src[pos] = s;
    csr_eid[pos] = e;
  }
}

__global__ void k_reorder_f(const float* __restrict__ eaM, const float* __restrict__ eaP,
                            const int* __restrict__ eid, float* __restrict__ ea_csr,
                            int EM, int ET, int edM, int edP, int edmax){
  int i = blockIdx.x*blockDim.x + threadIdx.x;
  if (i >= ET*edmax) return;
  int j = i/edmax, k = i - j*edmax;
  if (j < EM){
    if (k < edM) ea_csr[(size_t)j*edM + k] = eaM[(size_t)eid[j]*edM + k];
  } else {
    if (k < edP) ea_csr[(size_t)EM*edM + (size_t)(j-EM)*edP + k]
                 = eaP[(size_t)(eid[j]-EM)*edP + k];
  }
}

// ================= weight prep: Wt[n][k] bf16 (Wl||Wr as 256 cols), resWt[n][k] bf16 =================
__global__ void k_prep_w(const float* __restrict__ linlW_M, const float* __restrict__ linrW_M,
                         const float* __restrict__ resW_M,
                         const float* __restrict__ linlW_P, const float* __restrict__ linrW_P,
                         const float* __restrict__ resW_P,
                         ushort16* __restrict__ WtAll, ushort16* __restrict__ resWt){
  const int per = 256*CDIM + CDIM*CDIM;  // 49152
  int idx = blockIdx.x*blockDim.x + threadIdx.x;
  if (idx >= 6*per) return;
  int sl = idx / per; int rem = idx - sl*per;
  int s = sl / 3, l = sl % 3;
  const float* Wl = (s ? linlW_P : linlW_M) + (size_t)l*CDIM*CDIM;
  const float* Wr = (s ? linrW_P : linrW_M) + (size_t)l*CDIM*CDIM;
  const float* Rw = (s ? resW_P  : resW_M ) + (size_t)l*CDIM*CDIM;
  if (rem < 256*CDIM){
    int k = rem >> 8, n = rem & 255;
    float v = (n < CDIM) ? Wl[k*CDIM + n] : Wr[k*CDIM + (n-CDIM)];
    WtAll[((size_t)sl*256 + n)*CDIM + k] = f2bf(v);
  } else {
    int r2 = rem - 256*CDIM;
    int k = r2 >> 7, n = r2 & 127;
    resWt[((size_t)sl*CDIM + n)*CDIM + k] = f2bf(Rw[k*CDIM + n]);
  }
}

// ================= MFMA node transform (layer 0 only) =================
__global__ void __launch_bounds__(256, 6)
k_transform_mfma(const float* __restrict__ xM, const float* __restrict__ xP,
    const ushort16* __restrict__ WtM, const ushort16* __restrict__ WtP,
    const float* __restrict__ blM, const float* __restrict__ brM,
    const float* __restrict__ blP, const float* __restrict__ brP,
    ushort16* __restrict__ xlh, float* __restrict__ xr,
    int NM, int nb32M, int NP)
{
  __shared__ ushort16 xs[32*CDIM];
  __shared__ float   xro[32*CDIM];
  int tid = threadIdx.x;
  int b = blockIdx.x;
  const float* xin; const ushort16* Wt; const float *bl, *br;
  int n0, nn, outbase;
  if (b < nb32M){ xin=xM; n0=b*32; nn=min(32,NM-n0); outbase=n0; Wt=WtM; bl=blM; br=brM; }
  else { xin=xP; n0=(b-nb32M)*32; nn=min(32,NP-n0); outbase=NM+n0; Wt=WtP; bl=blP; br=brP; }
  for (int i = 0; i < 16; i++){
    int e = tid + i*256;
    int row = e >> 7, col = e & 127;
    float v = (row < nn) ? xin[(size_t)(n0+row)*CDIM + col] : 0.f;
    int byte = (row*256 + col*2) ^ ((row & 7) << 4);
    *(ushort16*)((char*)xs + byte) = f2bf(v);
  }
  __syncthreads();
  int w = tid >> 6, t = tid & 63;
  int r16 = t & 15, kg = t >> 4;
  floatx4 acc[2][4];
  #pragma unroll
  for (int m = 0; m < 2; m++)
    #pragma unroll
    for (int nb = 0; nb < 4; nb++) acc[m][nb] = (floatx4){0.f,0.f,0.f,0.f};
  #pragma unroll
  for (int ks = 0; ks < 4; ks++){
    short8 a[2];
    #pragma unroll
    for (int m = 0; m < 2; m++){
      int row = m*16 + r16;
      int byte = (row*256 + ks*64 + kg*16) ^ ((row & 7) << 4);
      a[m] = *(const short8*)((const char*)xs + byte);
    }
    #pragma unroll
    for (int nb = 0; nb < 4; nb++){
      int col = w*64 + nb*16 + r16;
      short8 bf = *(const short8*)(Wt + (size_t)col*CDIM + ks*32 + kg*8);
      #pragma unroll
      for (int m = 0; m < 2; m++)
        acc[m][nb] = __builtin_amdgcn_mfma_f32_16x16x32_bf16(a[m], bf, acc[m][nb], 0, 0, 0);
    }
  }
  __syncthreads();
  #pragma unroll
  for (int nb = 0; nb < 4; nb++){
    int col = w*64 + nb*16 + r16;
    float bias = (col < CDIM) ? bl[col] : br[col - CDIM];
    #pragma unroll
    for (int m = 0; m < 2; m++){
      #pragma unroll
      for (int reg = 0; reg < 4; reg++){
        int row = m*16 + kg*4 + reg;
        float v = acc[m][nb][reg] + bias;
        if (col < CDIM) xs[row*CDIM + col] = f2bf(v);
        else            xro[row*CDIM + (col - CDIM)] = v;
      }
    }
  }
  __syncthreads();
  for (int i = 0; i < 16; i++){
    int e = tid + i*256;
    int row = e >> 7, col = e & 127;
    if (row < nn){
      xlh[(size_t)(outbase+row)*CDIM + col] = xs[e];
      xr [(size_t)(outbase+row)*CDIM + col] = xro[e];
    }
  }
}

// ================= fused epilogue(l) + transform(l+1): h -> x (LDS only) -> xl,xr =================
__global__ void __launch_bounds__(256, 6)
k_fused_et(const float* __restrict__ hin,
    const ushort16* __restrict__ RtM, const ushort16* __restrict__ RtP,
    const float* __restrict__ RbM, const float* __restrict__ RbP,
    const ushort16* __restrict__ WtM, const ushort16* __restrict__ WtP,
    const float* __restrict__ blM, const float* __restrict__ brM,
    const float* __restrict__ blP, const float* __restrict__ brP,
    ushort16* __restrict__ xlh, float* __restrict__ xr,
    int NM, int nb32M, int NP)
{
  __shared__ ushort16 ab[32*CDIM];   // 8 KB: A-operand (h, then x), swizzled bf16; finally xl linear
  __shared__ float    hf[32*CDIM];   // 16 KB: h f32, then x f32, finally xr staging
  int tid = threadIdx.x;
  int b = blockIdx.x;
  const ushort16 *Rt, *Wt; const float *Rb, *bl, *br;
  int n0, nn, iobase;
  if (b < nb32M){ n0=b*32; nn=min(32,NM-n0); iobase=n0;
    Rt=RtM; Rb=RbM; Wt=WtM; bl=blM; br=brM; }
  else { n0=(b-nb32M)*32; nn=min(32,NP-n0); iobase=NM+n0;
    Rt=RtP; Rb=RbP; Wt=WtP; bl=blP; br=brP; }
  // phase 1: stage h
  for (int i = 0; i < 16; i++){
    int e = tid + i*256;
    int row = e >> 7, col = e & 127;
    float v = (row < nn) ? hin[(size_t)(iobase+row)*CDIM + col] : 0.f;
    hf[e] = v;
    int byte = (row*256 + col*2) ^ ((row & 7) << 4);
    *(ushort16*)((char*)ab + byte) = f2bf(v);
  }
  __syncthreads();
  int w = tid >> 6, t = tid & 63;
  int r16 = t & 15, kg = t >> 4;
  // phase 2: GEMM1 acc1 = h @ Rt  (N=128)
  floatx4 acc1[2][2];
  #pragma unroll
  for (int m = 0; m < 2; m++)
    #pragma unroll
    for (int nb = 0; nb < 2; nb++) acc1[m][nb] = (floatx4){0.f,0.f,0.f,0.f};
  #pragma unroll
  for (int ks = 0; ks < 4; ks++){
    short8 a[2];
    #pragma unroll
    for (int m = 0; m < 2; m++){
      int row = m*16 + r16;
      int byte = (row*256 + ks*64 + kg*16) ^ ((row & 7) << 4);
      a[m] = *(const short8*)((const char*)ab + byte);
    }
    #pragma unroll
    for (int nb = 0; nb < 2; nb++){
      int col = w*32 + nb*16 + r16;
      short8 bf = *(const short8*)(Rt + (size_t)col*CDIM + ks*32 + kg*8);
      #pragma unroll
      for (int m = 0; m < 2; m++)
        acc1[m][nb] = __builtin_amdgcn_mfma_f32_16x16x32_bf16(a[m], bf, acc1[m][nb], 0, 0, 0);
    }
  }
  __syncthreads();   // all reads of ab(h) done
  // phase 3: x = h + elu(acc1 + Rb) -> hf (f32, in place) + ab (swizzled bf16)
  #pragma unroll
  for (int nb = 0; nb < 2; nb++){
    int col = w*32 + nb*16 + r16;
    float rb = Rb[col];
    #pragma unroll
    for (int m = 0; m < 2; m++){
      #pragma unroll
      for (int reg = 0; reg < 4; reg++){
        int row = m*16 + kg*4 + reg;
        float r = acc1[m][nb][reg] + rb;
        float e = (r > 0.f) ? r : expm1f(r);
        float xv = hf[row*CDIM + col] + e;
        hf[row*CDIM + col] = xv;
        int byte = (row*256 + col*2) ^ ((row & 7) << 4);
        *(ushort16*)((char*)ab + byte) = f2bf(xv);
      }
    }
  }
  __syncthreads();
  // phase 4: GEMM2 acc2 = x @ Wt  (N=256)
  floatx4 acc2[2][4];
  #pragma unroll
  for (int m = 0; m < 2; m++)
    #pragma unroll
    for (int nb = 0; nb < 4; nb++) acc2[m][nb] = (floatx4){0.f,0.f,0.f,0.f};
  #pragma unroll
  for (int ks = 0; ks < 4; ks++){
    short8 a[2];
    #pragma unroll
    for (int m = 0; m < 2; m++){
      int row = m*16 + r16;
      int byte = (row*256 + ks*64 + kg*16) ^ ((row & 7) << 4);
      a[m] = *(const short8*)((const char*)ab + byte);
    }
    #pragma unroll
    for (int nb = 0; nb < 4; nb++){
      int col = w*64 + nb*16 + r16;
      short8 bf = *(const short8*)(Wt + (size_t)col*CDIM + ks*32 + kg*8);
      #pragma unroll
      for (int m = 0; m < 2; m++)
        acc2[m][nb] = __builtin_amdgcn_mfma_f32_16x16x32_bf16(a[m], bf, acc2[m][nb], 0, 0, 0);
    }
  }
  __syncthreads();   // all reads of ab(x) done
  // phase 5: scatter xl->ab (linear bf16), xr->hf (linear f32)
  #pragma unroll
  for (int nb = 0; nb < 4; nb++){
    int col = w*64 + nb*16 + r16;
    float bias = (col < CDIM) ? bl[col] : br[col - CDIM];
    #pragma unroll
    for (int m = 0; m < 2; m++){
      #pragma unroll
      for (int reg = 0; reg < 4; reg++){
        int row = m*16 + kg*4 + reg;
        float v = acc2[m][nb][reg] + bias;
        if (col < CDIM) ab[row*CDIM + col] = f2bf(v);
        else            hf[row*CDIM + (col - CDIM)] = v;
      }
    }
  }
  __syncthreads();
  // phase 6: coalesced writes
  for (int i = 0; i < 16; i++){
    int e = tid + i*256;
    int row = e >> 7, col = e & 127;
    if (row < nn){
      xlh[(size_t)(iobase+row)*CDIM + col] = ab[e];
      xr [(size_t)(iobase+row)*CDIM + col] = hf[e];
    }
  }
}

// ================= fused GAT aggregation (software-pipelined gathers, defer-max) =================
template<int ED>
__device__ __forceinline__ void gat_edges(
    int start, int end, int t, int j0, int ed_rt,
    const uint32* __restrict__ xlu, float2 xrv, float2 at2,
    const float2* __restrict__ lw2,
    const float* __restrict__ ea, const int* __restrict__ csr_src,
    float& m, float& den, float& a0, float& a1)
{
  const int ed = (ED > 0) ? ED : ed_rt;
  if (start >= end) return;
  // preload first batch
  int j = start;
  int r = end - j;
  int jj1 = (1 < r) ? j+1 : j;
  int jj2 = (2 < r) ? j+2 : j;
  int jj3 = (3 < r) ? j+3 : j;
  int e0 = __builtin_amdgcn_readfirstlane(j   - j0);
  int e1 = __builtin_amdgcn_readfirstlane(jj1 - j0);
  int e2 = __builtin_amdgcn_readfirstlane(jj2 - j0);
  int e3 = __builtin_amdgcn_readfirstlane(jj3 - j0);
  int s0 = __builtin_amdgcn_readfirstlane(csr_src[j]);
  int s1 = __builtin_amdgcn_readfirstlane(csr_src[jj1]);
  int s2 = __builtin_amdgcn_readfirstlane(csr_src[jj2]);
  int s3 = __builtin_amdgcn_readfirstlane(csr_src[jj3]);
  uint32 u0 = xlu[(size_t)s0*64 + t];
  uint32 u1 = xlu[(size_t)s1*64 + t];
  uint32 u2 = xlu[(size_t)s2*64 + t];
  uint32 u3 = xlu[(size_t)s3*64 + t];
  while (j < end){
    // save current batch regs
    uint32 c0 = u0, c1 = u1, c2 = u2, c3 = u3;
    int ce0 = e0, ce1 = e1, ce2 = e2, ce3 = e3;
    int cr = r;
    int nj = j + 4;
    // prefetch next batch (loads in flight across the compute below)
    if (nj < end){
      r = end - nj;
      jj1 = (1 < r) ? nj+1 : nj;
      jj2 = (2 < r) ? nj+2 : nj;
      jj3 = (3 < r) ? nj+3 : nj;
      e0 = __builtin_amdgcn_readfirstlane(nj  - j0);
      e1 = __builtin_amdgcn_readfirstlane(jj1 - j0);
      e2 = __builtin_amdgcn_readfirstlane(jj2 - j0);
      e3 = __builtin_amdgcn_readfirstlane(jj3 - j0);
      s0 = __builtin_amdgcn_readfirstlane(csr_src[nj]);
      s1 = __builtin_amdgcn_readfirstlane(csr_src[jj1]);
      s2 = __builtin_amdgcn_readfirstlane(csr_src[jj2]);
      s3 = __builtin_amdgcn_readfirstlane(csr_src[jj3]);
      u0 = xlu[(size_t)s0*64 + t];
      u1 = xlu[(size_t)s1*64 + t];
      u2 = xlu[(size_t)s2*64 + t];
      u3 = xlu[(size_t)s3*64 + t];
    }
    // ---- compute current batch ----
    const float* p0 = ea + (size_t)ce0*ed;
    const float* p1 = ea + (size_t)ce1*ed;
    const float* p2 = ea + (size_t)ce2*ed;
    const float* p3 = ea + (size_t)ce3*ed;
    float x0x = __uint_as_float(c0 << 16), x0y = __uint_as_float(c0 & 0xffff0000u);
    float x1x = __uint_as_float(c1 << 16), x1y = __uint_as_float(c1 & 0xffff0000u);
    float x2x = __uint_as_float(c2 << 16), x2y = __uint_as_float(c2 & 0xffff0000u);
    float x3x = __uint_as_float(c3 << 16), x3y = __uint_as_float(c3 & 0xffff0000u);
    float em00=0.f, em01=0.f, em10=0.f, em11=0.f;
    float em20=0.f, em21=0.f, em30=0.f, em31=0.f;
    #pragma unroll 4
    for (int k = 0; k < ed; k++){
      float2 lwv = lw2[k*64 + t];
      float a = p0[k], bq = p1[k], c = p2[k], d = p3[k];
      em00 = fmaf(a,  lwv.x, em00); em01 = fmaf(a,  lwv.y, em01);
      em10 = fmaf(bq, lwv.x, em10); em11 = fmaf(bq, lwv.y, em11);
      em20 = fmaf(c,  lwv.x, em20); em21 = fmaf(c,  lwv.y, em21);
      em30 = fmaf(d,  lwv.x, em30); em31 = fmaf(d,  lwv.y, em31);
    }
    float m00 = x0x + xrv.x + em00; m00 = (m00>=0.f)?m00:0.2f*m00;
    float m01 = x0y + xrv.y + em01; m01 = (m01>=0.f)?m01:0.2f*m01;
    float m10 = x1x + xrv.x + em10; m10 = (m10>=0.f)?m10:0.2f*m10;
    float m11 = x1y + xrv.y + em11; m11 = (m11>=0.f)?m11:0.2f*m11;
    float m20 = x2x + xrv.x + em20; m20 = (m20>=0.f)?m20:0.2f*m20;
    float m21 = x2y + xrv.y + em21; m21 = (m21>=0.f)?m21:0.2f*m21;
    float m30 = x3x + xrv.x + em30; m30 = (m30>=0.f)?m30:0.2f*m30;
    float m31 = x3y + xrv.y + em31; m31 = (m31>=0.f)?m31:0.2f*m31;
    float v0 = fmaf(m00, at2.x, m01*at2.y);
    float v1 = fmaf(m10, at2.x, m11*at2.y);
    float v2 = fmaf(m20, at2.x, m21*at2.y);
    float v3 = fmaf(m30, at2.x, m31*at2.y);
    #pragma unroll
    for (int off = 1; off < 8; off <<= 1){
      v0 += __shfl_xor(v0, off, 8);
      v1 += __shfl_xor(v1, off, 8);
      v2 += __shfl_xor(v2, off, 8);
      v3 += __shfl_xor(v3, off, 8);
    }
    if (1 >= cr) v1 = -INFINITY;
    if (2 >= cr) v2 = -INFINITY;
    if (3 >= cr) v3 = -INFINITY;
    float vmax = fmaxf(fmaxf(v0, v1), fmaxf(v2, v3));
    if (vmax > m + 8.f){
      float sc = __expf(m - vmax);   // m=-inf first time -> sc=0
      den *= sc; a0 *= sc; a1 *= sc; m = vmax;
    }
    float w0 = __expf(v0 - m), w1 = __expf(v1 - m);
    float w2 = __expf(v2 - m), w3 = __expf(v3 - m);
    den += (w0 + w1) + (w2 + w3);
    a0 = fmaf(w0, x0x, fmaf(w1, x1x, fmaf(w2, x2x, fmaf(w3, x3x, a0))));
    a1 = fmaf(w0, x0y, fmaf(w1, x1y, fmaf(w2, x2y, fmaf(w3, x3y, a1))));
    j = nj;
  }
}

template<int EDM_T, int EDP_T>
__global__ void __launch_bounds__(256, 8)
k_gat_f(const uint32* __restrict__ xlu, const float2* __restrict__ xr2,
    const float* __restrict__ eaM, const float* __restrict__ eaP,
    const float* __restrict__ lwM, const float* __restrict__ atM, const float* __restrict__ biM,
    const float* __restrict__ lwP, const float* __restrict__ atP, const float* __restrict__ biP,
    const int* __restrict__ rowptr, const int* __restrict__ csr_src,
    float2* __restrict__ hout2, int NM, int NT, int EM, int edM_rt, int edP_rt)
{
  const int edM = (EDM_T > 0) ? EDM_T : edM_rt;
  const int edP = (EDP_T > 0) ? EDP_T : edP_rt;
  __shared__ float lw[24*CDIM];
  int tb = threadIdx.x;
  for (int i = tb; i < edM*CDIM; i += 256) lw[i] = lwM[i];
  for (int i = tb; i < edP*CDIM; i += 256) lw[edM*CDIM + i] = lwP[i];
  __syncthreads();
  int w = tb >> 6;
  int t = tb & 63;
  const float2* lwM2 = (const float2*)lw;
  const float2* lwP2 = (const float2*)(lw + edM*CDIM);
  float2 at2M = ((const float2*)atM)[t];
  float2 at2P = ((const float2*)atP)[t];
  float2 bb2M = ((const float2*)biM)[t];
  float2 bb2P = ((const float2*)biP)[t];
  for (int n = blockIdx.x*4 + w; n < NT; n += gridDim.x*4){
    bool mg = (n < NM);
    float2 xrv = xr2[(size_t)n*64 + t];
    int start = __builtin_amdgcn_readfirstlane(rowptr[n]);
    int end   = __builtin_amdgcn_readfirstlane(rowptr[n+1]);
    float m = -INFINITY, den = 0.f, a0 = 0.f, a1 = 0.f;
    if (mg)
      gat_edges<EDM_T>(start, end, t, 0, edM, xlu, xrv, at2M, lwM2,
                       eaM, csr_src, m, den, a0, a1);
    else
      gat_edges<EDP_T>(start, end, t, EM, edP, xlu, xrv, at2P, lwP2,
                       eaP, csr_src, m, den, a0, a1);
    float2 bb2 = mg ? bb2M : bb2P;
    float inv = 1.f/(den + 1e-16f);
    hout2[(size_t)n*64 + t] = make_float2(fmaf(a0, inv, bb2.x), fmaf(a1, inv, bb2.y));
  }
}

// ================= MFMA epilogue (layer 2: residual + pool) =================
__global__ void __launch_bounds__(256, 6)
k_epilogue_mfma(const float* __restrict__ hin,
    const ushort16* __restrict__ RtM, const ushort16* __restrict__ RtP,
    const float* __restrict__ RbM, const float* __restrict__ RbP,
    int NM, int nb32M, int NP,
    const int* __restrict__ batchM, const int* __restrict__ batchP,
    float* __restrict__ pool)
{
  __shared__ ushort16 hb[32*CDIM];
  __shared__ float hf[32*CDIM];
  int tid = threadIdx.x;
  int b = blockIdx.x;
  const ushort16* Rt; const float* Rb; const int* batch;
  int n0, nn, iobase, off;
  if (b < nb32M){ n0=b*32; nn=min(32,NM-n0); iobase=n0; Rt=RtM; Rb=RbM; batch=batchM; off=0; }
  else { n0=(b-nb32M)*32; nn=min(32,NP-n0); iobase=NM+n0; Rt=RtP; Rb=RbP; batch=batchP; off=CDIM; }
  for (int i = 0; i < 16; i++){
    int e = tid + i*256;
    int row = e >> 7, col = e & 127;
    float v = (row < nn) ? hin[(size_t)(iobase+row)*CDIM + col] : 0.f;
    hf[e] = v;
    int byte = (row*256 + col*2) ^ ((row & 7) << 4);
    *(ushort16*)((char*)hb + byte) = f2bf(v);
  }
  __syncthreads();
  int w = tid >> 6, t = tid & 63;
  int r16 = t & 15, kg = t >> 4;
  floatx4 acc[2][2];
  #pragma unroll
  for (int m = 0; m < 2; m++)
    #pragma unroll
    for (int nb = 0; nb < 2; nb++) acc[m][nb] = (floatx4){0.f,0.f,0.f,0.f};
  #pragma unroll
  for (int ks = 0; ks < 4; ks++){
    short8 a[2];
    #pragma unroll
    for (int m = 0; m < 2; m++){
      int row = m*16 + r16;
      int byte = (row*256 + ks*64 + kg*16) ^ ((row & 7) << 4);
      a[m] = *(const short8*)((const char*)hb + byte);
    }
    #pragma unroll
    for (int nb = 0; nb < 2; nb++){
      int col = w*32 + nb*16 + r16;
      short8 bf = *(const short8*)(Rt + (size_t)col*CDIM + ks*32 + kg*8);
      #pragma unroll
      for (int m = 0; m < 2; m++)
        acc[m][nb] = __builtin_amdgcn_mfma_f32_16x16x32_bf16(a[m], bf, acc[m][nb], 0, 0, 0);
    }
  }
  #pragma unroll
  for (int nb = 0; nb < 2; nb++){
    int col = w*32 + nb*16 + r16;
    float rb = Rb[col];
    #pragma unroll
    for (int m = 0; m < 2; m++){
      #pragma unroll
      for (int reg = 0; reg < 4; reg++){
        int row = m*16 + kg*4 + reg;
        float r = acc[m][nb][reg] + rb;
        float e = (r > 0.f) ? r : expm1f(r);
        hf[row*CDIM + col] = hf[row*CDIM + col] + e;
      }
    }
  }
  __syncthreads();
  for (int i = 0; i < 16; i++){
    int e = tid + i*256;
    int row = e >> 7, col = e & 127;
    if (row < nn){
      int g = batch[n0 + row];
      atomicAdd(&pool[(size_t)g*256 + off + col], hf[e]);
    }
  }
}

// ================= head =================
__global__ void k_head(const float* __restrict__ pool,
    const float* __restrict__ fc1W, const float* __restrict__ fc1b,
    const float* __restrict__ fc2W, const float* __restrict__ fc2b,
    float* __restrict__ out)
{
  __shared__ float ps[256];
  __shared__ float zs[CDIM];
  int g = blockIdx.x, t = threadIdx.x;
  ps[t]       = pool[g*256 + t];
  ps[t + 128] = pool[g*256 + 128 + t];
  __syncthreads();
  float acc = 0.f;
  for (int k = 0; k < 256; k++) acc = fmaf(ps[k], fc1W[k*CDIM + t], acc);
  acc += fc1b[t];
  float z = (acc > 0.f) ? acc : expm1f(acc);
  zs[t] = z * fc2W[t];
  __syncthreads();
  for (int s = 64; s > 0; s >>= 1){
    if (t < s) zs[t] += zs[t + s];
    __syncthreads();
  }
  if (t == 0){
    float o = zs[0] + fc2b[0];
    out[g] = 1.f / (1.f + expf(-o));
  }
}

extern "C" void kernel_launch(void* const* d_in, const int* in_sizes, int n_in,
                              void* d_out, int out_size, void* d_ws, size_t ws_size,
                              hipStream_t stream)
{
  const int NM = in_sizes[0] / CDIM, NP = in_sizes[1] / CDIM;
  const int EM = in_sizes[26] / 2,   EP = in_sizes[27] / 2;
  const int edM = in_sizes[2] / EM,  edP = in_sizes[3] / EP;
  const int NT = NM + NP, ET = EM + EP;
  const int edmax = (edM > edP) ? edM : edP;

  const int nb32M = (NM + 31)/32, nb32P = (NP + 31)/32;
  const int nbT32 = nb32M + nb32P;
  const int nbScan = (NT + 1023)/1024;

  float* Wp = (float*)d_ws;
  float* x      = Wp;                                  // NT*128 f32 (unused now; kept for layout)
  ushort16* xlh = (ushort16*)(x + (size_t)NT*CDIM);    // NT*128 bf16
  float* xr     = (float*)(xlh) + (size_t)NT*64;       // NT*128 f32 (hout aliases)
  float* pool   = xr + (size_t)NT*CDIM;                // NG*256
  int* rowptr  = (int*)(pool + (size_t)NG*256);        // NT+1
  int* deg     = rowptr + NT + 1;
  int* cursor  = deg + NT;
  int* sums    = cursor + NT;                          // nbScan+1
  int* csr_src = sums + nbScan + 1;                    // ET
  int* csr_eid = csr_src + ET;                         // ET
  float* ea_csr = (float*)(csr_eid + ET);              // EM*edM + EP*edP
  size_t ea_elems = (size_t)EM*edM + (size_t)EP*edP;
  ushort16* WtAll = (ushort16*)(ea_csr + ea_elems);    // 6*256*128 bf16
  ushort16* resWt = WtAll + (size_t)6*256*CDIM;        // 6*128*128 bf16

  size_t need = ((size_t)NT*CDIM + (size_t)NT*64 + (size_t)NT*CDIM + (size_t)NG*256)*4
              + ((size_t)3*NT + 1 + nbScan + 1 + (size_t)2*ET)*4
              + ea_elems*4
              + ((size_t)6*256*CDIM + (size_t)6*CDIM*CDIM)*2;
  if (ws_size < need) return;

  const float* xM0    = (const float*)d_in[0];
  const float* xP0    = (const float*)d_in[1];
  const float* eattrM = (const float*)d_in[2];
  const float* eattrP = (const float*)d_in[3];
  const int* eiM = (const int*)d_in[26];
  const int* eiP = (const int*)d_in[27];
  const int* batchM = (const int*)d_in[28];
  const int* batchP = (const int*)d_in[29];
  const int* srcM = eiM, *dstM = eiM + EM;
  const int* srcP = eiP, *dstP = eiP + EP;

  hipMemsetAsync(pool, 0, (size_t)NG*256*sizeof(float), stream);
  hipMemsetAsync(deg, 0, (size_t)NT*sizeof(int), stream);

  // ---- weight prep (once) ----
  {
    const int tot = 6*(256*CDIM + CDIM*CDIM);
    k_prep_w<<<(tot + 255)/256, 256, 0, stream>>>(
        (const float*)d_in[4], (const float*)d_in[6], (const float*)d_in[11],
        (const float*)d_in[13], (const float*)d_in[15], (const float*)d_in[20],
        WtAll, resWt);
  }

  // ---- unified CSR build ----
  k_count_f<<<(ET + 255)/256, 256, 0, stream>>>(dstM, dstP, deg, EM, ET, NM);
  k_scan1<<<nbScan, 1024, 0, stream>>>(deg, rowptr, sums, NT);
  k_scan2<<<1, 1024, 0, stream>>>(sums, nbScan);
  k_scan3<<<(NT + 255)/256, 256, 0, stream>>>(rowptr, cursor, sums, NT, nbScan);
  k_scatter_f<<<(ET + 255)/256, 256, 0, stream>>>(srcM, srcP, dstM, dstP, cursor,
                                                  csr_src, csr_eid, EM, ET, NM);
  k_reorder_f<<<((size_t)ET*edmax + 255)/256, 256, 0, stream>>>(
      eattrM, eattrP, csr_eid, ea_csr, EM, ET, edM, edP, edmax);
  const float* eaM_use = ea_csr;
  const float* eaP_use = ea_csr + (size_t)EM*edM;

  int gatBlocks = (NT + 3)/4;
  if (gatBlocks > 2048) gatBlocks = 2048;

  // per-layer parameter pointers
  auto runGat = [&](int l){
    const float* WeM = (const float*)d_in[8]  + (size_t)l*edM*CDIM;
    const float* atM = (const float*)d_in[9]  + (size_t)l*CDIM;
    const float* biM = (const float*)d_in[10] + (size_t)l*CDIM;
    const float* WeP = (const float*)d_in[17] + (size_t)l*edP*CDIM;
    const float* atP = (const float*)d_in[18] + (size_t)l*CDIM;
    const float* biP = (const float*)d_in[19] + (size_t)l*CDIM;
    if (edM == 8 && edP == 12)
      k_gat_f<8,12><<<gatBlocks, 256, 0, stream>>>((const uint32*)xlh, (const float2*)xr,
          eaM_use, eaP_use, WeM, atM, biM, WeP, atP, biP,
          rowptr, csr_src, (float2*)xr, NM, NT, EM, edM, edP);
    else
      k_gat_f<0,0><<<gatBlocks, 256, 0, stream>>>((const uint32*)xlh, (const float2*)xr,
          eaM_use, eaP_use, WeM, atM, biM, WeP, atP, biP,
          rowptr, csr_src, (float2*)xr, NM, NT, EM, edM, edP);
  };

  // layer 0 transform
  k_transform_mfma<<<nbT32, 256, 0, stream>>>(xM0, xP0,
      WtAll + 0*(size_t)256*CDIM, WtAll + 3*(size_t)256*CDIM,
      (const float*)d_in[5], (const float*)d_in[7],
      (const float*)d_in[14], (const float*)d_in[16],
      xlh, xr, NM, nb32M, NP);
  runGat(0);
  // boundaries: epilogue(l) + transform(l+1)
  for (int l = 0; l < 2; l++){
    k_fused_et<<<nbT32, 256, 0, stream>>>(xr,
        resWt + (size_t)(0*3 + l)*CDIM*CDIM, resWt + (size_t)(1*3 + l)*CDIM*CDIM,
        (const float*)d_in[12] + (size_t)l*CDIM, (const float*)d_in[21] + (size_t)l*CDIM,
        WtAll + (size_t)(0*3 + l+1)*256*CDIM, WtAll + (size_t)(1*3 + l+1)*256*CDIM,
        (const float*)d_in[5]  + (size_t)(l+1)*CDIM, (const float*)d_in[7]  + (size_t)(l+1)*CDIM,
        (const float*)d_in[14] + (size_t)(l+1)*CDIM, (const float*)d_in[16] + (size_t)(l+1)*CDIM,
        xlh, xr, NM, nb32M, NP);
    runGat(l+1);
  }
  // layer 2 epilogue + pool
  k_epilogue_mfma<<<nbT32, 256, 0, stream>>>(xr,
      resWt + (size_t)(0*3 + 2)*CDIM*CDIM, resWt + (size_t)(1*3 + 2)*CDIM*CDIM,
      (const float*)d_in[12] + (size_t)2*CDIM, (const float*)d_in[21] + (size_t)2*CDIM,
      NM, nb32M, NP, batchM, batchP, pool);

  const float* fc1W = (const float*)d_in[22];
  const float* fc1b = (const float*)d_in[23];
  const float* fc2W = (const float*)d_in[24];
  const float* fc2b = (const float*)d_in[25];
  k_head<<<NG, 128, 0, stream>>>(pool, fc1W, fc1b, fc2W, fc2b, (float*)d_out);
}

// Round 14
// 633.536 us; speedup vs baseline: 1.1074x; 1.1074x over previous
//
#include <hip/hip_runtime.h>
#include <hip/hip_bf16.h>

#define CDIM 128
#define NG 128
typedef unsigned int uint32;
typedef unsigned short ushort16;
typedef __attribute__((ext_vector_type(8))) short short8;
typedef __attribute__((ext_vector_type(4))) float floatx4;

__device__ __forceinline__ ushort16 f2bf(float f){
  uint32 u = __float_as_uint(f);
  u = (u + 0x7fffu + ((u >> 16) & 1u)) >> 16;   // RNE
  return (ushort16)u;
}

// ================= CSR build (unified graph: mg nodes [0,NM), pg nodes [NM,NT)) =================
__global__ void k_count_f(const int* __restrict__ dstM, const int* __restrict__ dstP,
                          int* __restrict__ deg, int EM, int ET, int NM){
  int e = blockIdx.x*blockDim.x + threadIdx.x;
  if (e < ET){
    int d = (e < EM) ? dstM[e] : dstP[e-EM] + NM;
    atomicAdd(&deg[d], 1);
  }
}

__global__ void k_scan1(const int* __restrict__ deg, int* __restrict__ rowptr,
                        int* __restrict__ sums, int N){
  __shared__ int tmp[1024];
  int b = blockIdx.x, t = threadIdx.x;
  int i = b*1024 + t;
  int v = (i < N) ? deg[i] : 0;
  tmp[t] = v; __syncthreads();
  for (int off = 1; off < 1024; off <<= 1){
    int a = (t >= off) ? tmp[t-off] : 0;
    __syncthreads();
    tmp[t] += a;
    __syncthreads();
  }
  if (i < N) rowptr[i] = tmp[t] - v;
  if (t == 1023) sums[b] = tmp[t];
}

__global__ void k_scan2(int* __restrict__ sums, int nb){
  __shared__ int tmp[1024];
  __shared__ int carry;
  int t = threadIdx.x;
  if (t == 0) carry = 0;
  __syncthreads();
  for (int base = 0; base < nb; base += 1024){
    int i = base + t;
    int v = (i < nb) ? sums[i] : 0;
    tmp[t] = v; __syncthreads();
    for (int off = 1; off < 1024; off <<= 1){
      int a = (t >= off) ? tmp[t-off] : 0;
      __syncthreads();
      tmp[t] += a;
      __syncthreads();
    }
    if (i < nb) sums[i] = carry + tmp[t] - v;
    int tot = tmp[1023];
    __syncthreads();
    if (t == 0) carry += tot;
    __syncthreads();
  }
  if (t == 0) sums[nb] = carry;
}

__global__ void k_scan3(int* __restrict__ rowptr, int* __restrict__ cursor,
                        const int* __restrict__ sums, int N, int nb){
  int i = blockIdx.x*blockDim.x + threadIdx.x;
  if (i < N){
    int r = rowptr[i] + sums[i >> 10];
    rowptr[i] = r; cursor[i] = r;
  }
  if (i == 0) rowptr[N] = sums[nb];
}

__global__ void k_scatter_f(const int* __restrict__ srcM, const int* __restrict__ srcP,
                            const int* __restrict__ dstM, const int* __restrict__ dstP,
                            int* __restrict__ cursor, int* __restrict__ csr_src,
                            int* __restrict__ csr_eid, int EM, int ET, int NM){
  int e = blockIdx.x*blockDim.x + threadIdx.x;
  if (e < ET){
    int s, d;
    if (e < EM){ s = srcM[e]; d = dstM[e]; }
    else       { s = srcP[e-EM] + NM; d = dstP[e-EM] + NM; }
    int pos = atomicAdd(&cursor[d], 1);
    csr_src[pos] = s;
    csr_eid[pos] = e;
  }
}

__global__ void k_reorder_f(const float* __restrict__ eaM, const float* __restrict__ eaP,
                            const int* __restrict__ eid, float* __restrict__ ea_csr,
                            int EM, int ET, int edM, int edP, int edmax){
  int i = blockIdx.x*blockDim.x + threadIdx.x;
  if (i >= ET*edmax) return;
  int j = i/edmax, k = i - j*edmax;
  if (j < EM){
    if (k < edM) ea_csr[(size_t)j*edM + k] = eaM[(size_t)eid[j]*edM + k];
  } else {
    if (k < edP) ea_csr[(size_t)EM*edM + (size_t)(j-EM)*edP + k]
                 = eaP[(size_t)(eid[j]-EM)*edP + k];
  }
}

// ================= weight prep: Wt[n][k] bf16 (Wl||Wr as 256 cols), resWt[n][k] bf16 =================
__global__ void k_prep_w(const float* __restrict__ linlW_M, const float* __restrict__ linrW_M,
                         const float* __restrict__ resW_M,
                         const float* __restrict__ linlW_P, const float* __restrict__ linrW_P,
                         const float* __restrict__ resW_P,
                         ushort16* __restrict__ WtAll, ushort16* __restrict__ resWt){
  const int per = 256*CDIM + CDIM*CDIM;  // 49152
  int idx = blockIdx.x*blockDim.x + threadIdx.x;
  if (idx >= 6*per) return;
  int sl = idx / per; int rem = idx - sl*per;
  int s = sl / 3, l = sl % 3;
  const float* Wl = (s ? linlW_P : linlW_M) + (size_t)l*CDIM*CDIM;
  const float* Wr = (s ? linrW_P : linrW_M) + (size_t)l*CDIM*CDIM;
  const float* Rw = (s ? resW_P  : resW_M ) + (size_t)l*CDIM*CDIM;
  if (rem < 256*CDIM){
    int k = rem >> 8, n = rem & 255;     // coalesced reads along n
    float v = (n < CDIM) ? Wl[k*CDIM + n] : Wr[k*CDIM + (n-CDIM)];
    WtAll[((size_t)sl*256 + n)*CDIM + k] = f2bf(v);
  } else {
    int r2 = rem - 256*CDIM;
    int k = r2 >> 7, n = r2 & 127;
    resWt[((size_t)sl*CDIM + n)*CDIM + k] = f2bf(Rw[k*CDIM + n]);
  }
}

// ================= MFMA node transform: [xl|xr] = x @ [Wl|Wr] + [bl|br] =================
// Output staged through LDS -> fully coalesced global writes (no 64B partial-line RFO).
__global__ void __launch_bounds__(256, 6)
k_transform_mfma(const float* __restrict__ xM, const float* __restrict__ xP,
    const ushort16* __restrict__ WtM, const ushort16* __restrict__ WtP,   // [256][128] bf16
    const float* __restrict__ blM, const float* __restrict__ brM,
    const float* __restrict__ blP, const float* __restrict__ brP,
    ushort16* __restrict__ xlh, float* __restrict__ xr,
    int NM, int nb32M, int NP)
{
  __shared__ ushort16 xs[32*CDIM];   // 8 KB: input bf16 swizzled; reused as xl output (linear)
  __shared__ float   xro[32*CDIM];   // 16 KB: xr output staging
  int tid = threadIdx.x;
  int b = blockIdx.x;
  const float* xin; const ushort16* Wt; const float *bl, *br;
  int n0, nn, outbase;
  if (b < nb32M){ xin=xM; n0=b*32; nn=min(32,NM-n0); outbase=n0; Wt=WtM; bl=blM; br=brM; }
  else { xin=xP; n0=(b-nb32M)*32; nn=min(32,NP-n0); outbase=NM+n0; Wt=WtP; bl=blP; br=brP; }
  // phase 1: stage input (coalesced read, swizzled bf16 LDS write)
  for (int i = 0; i < 16; i++){
    int e = tid + i*256;            // 0..4095
    int row = e >> 7, col = e & 127;
    float v = (row < nn) ? xin[(size_t)(n0+row)*CDIM + col] : 0.f;
    int byte = (row*256 + col*2) ^ ((row & 7) << 4);
    *(ushort16*)((char*)xs + byte) = f2bf(v);
  }
  __syncthreads();
  // phase 2: MFMA
  int w = tid >> 6, t = tid & 63;
  int r16 = t & 15, kg = t >> 4;
  floatx4 acc[2][4];
  #pragma unroll
  for (int m = 0; m < 2; m++)
    #pragma unroll
    for (int nb = 0; nb < 4; nb++) acc[m][nb] = (floatx4){0.f,0.f,0.f,0.f};
  #pragma unroll
  for (int ks = 0; ks < 4; ks++){
    short8 a[2];
    #pragma unroll
    for (int m = 0; m < 2; m++){
      int row = m*16 + r16;
      int byte = (row*256 + ks*64 + kg*16) ^ ((row & 7) << 4);
      a[m] = *(const short8*)((const char*)xs + byte);
    }
    #pragma unroll
    for (int nb = 0; nb < 4; nb++){
      int col = w*64 + nb*16 + r16;
      short8 bf = *(const short8*)(Wt + (size_t)col*CDIM + ks*32 + kg*8);
      #pragma unroll
      for (int m = 0; m < 2; m++)
        acc[m][nb] = __builtin_amdgcn_mfma_f32_16x16x32_bf16(a[m], bf, acc[m][nb], 0, 0, 0);
    }
  }
  __syncthreads();   // xs reads done — safe to overwrite
  // phase 3: scatter fragments into LDS (cheap)
  #pragma unroll
  for (int nb = 0; nb < 4; nb++){
    int col = w*64 + nb*16 + r16;
    float bias = (col < CDIM) ? bl[col] : br[col - CDIM];
    #pragma unroll
    for (int m = 0; m < 2; m++){
      #pragma unroll
      for (int reg = 0; reg < 4; reg++){
        int row = m*16 + kg*4 + reg;
        float v = acc[m][nb][reg] + bias;
        if (col < CDIM) xs[row*CDIM + col] = f2bf(v);       // linear ushort
        else            xro[row*CDIM + (col - CDIM)] = v;
      }
    }
  }
  __syncthreads();
  // phase 4: coalesced global writes (full lines)
  for (int i = 0; i < 16; i++){
    int e = tid + i*256;
    int row = e >> 7, col = e & 127;
    if (row < nn){
      xlh[(size_t)(outbase+row)*CDIM + col] = xs[e];
      xr [(size_t)(outbase+row)*CDIM + col] = xro[e];
    }
  }
}

// ================= fused GAT aggregation (round-9/11 structure) =================
template<int ED>
__device__ __forceinline__ void gat_edges(
    int start, int end, int t, int j0, int ed_rt,
    const uint32* __restrict__ xlu, float2 xrv, float2 at2,
    const float2* __restrict__ lw2,
    const float* __restrict__ ea, const int* __restrict__ csr_src,
    float& m, float& den, float& a0, float& a1)
{
  const int ed = (ED > 0) ? ED : ed_rt;
  for (int j = start; j < end; j += 4){
    const int r = end - j;
    int jj1 = (1 < r) ? j+1 : j;
    int jj2 = (2 < r) ? j+2 : j;
    int jj3 = (3 < r) ? j+3 : j;
    int s0 = __builtin_amdgcn_readfirstlane(csr_src[j]);
    int s1 = __builtin_amdgcn_readfirstlane(csr_src[jj1]);
    int s2 = __builtin_amdgcn_readfirstlane(csr_src[jj2]);
    int s3 = __builtin_amdgcn_readfirstlane(csr_src[jj3]);
    int e0 = __builtin_amdgcn_readfirstlane(j   - j0);
    int e1 = __builtin_amdgcn_readfirstlane(jj1 - j0);
    int e2 = __builtin_amdgcn_readfirstlane(jj2 - j0);
    int e3 = __builtin_amdgcn_readfirstlane(jj3 - j0);
    const float* p0 = ea + (size_t)e0*ed;
    const float* p1 = ea + (size_t)e1*ed;
    const float* p2 = ea + (size_t)e2*ed;
    const float* p3 = ea + (size_t)e3*ed;
    uint32 u0 = xlu[(size_t)s0*64 + t];
    uint32 u1 = xlu[(size_t)s1*64 + t];
    uint32 u2 = xlu[(size_t)s2*64 + t];
    uint32 u3 = xlu[(size_t)s3*64 + t];
    float x0x = __uint_as_float(u0 << 16), x0y = __uint_as_float(u0 & 0xffff0000u);
    float x1x = __uint_as_float(u1 << 16), x1y = __uint_as_float(u1 & 0xffff0000u);
    float x2x = __uint_as_float(u2 << 16), x2y = __uint_as_float(u2 & 0xffff0000u);
    float x3x = __uint_as_float(u3 << 16), x3y = __uint_as_float(u3 & 0xffff0000u);
    float em00=0.f, em01=0.f, em10=0.f, em11=0.f;
    float em20=0.f, em21=0.f, em30=0.f, em31=0.f;
    #pragma unroll 4
    for (int k = 0; k < ed; k++){
      float2 lwv = lw2[k*64 + t];
      float a = p0[k], bq = p1[k], c = p2[k], d = p3[k];
      em00 = fmaf(a,  lwv.x, em00); em01 = fmaf(a,  lwv.y, em01);
      em10 = fmaf(bq, lwv.x, em10); em11 = fmaf(bq, lwv.y, em11);
      em20 = fmaf(c,  lwv.x, em20); em21 = fmaf(c,  lwv.y, em21);
      em30 = fmaf(d,  lwv.x, em30); em31 = fmaf(d,  lwv.y, em31);
    }
    float m00 = x0x + xrv.x + em00; m00 = (m00>=0.f)?m00:0.2f*m00;
    float m01 = x0y + xrv.y + em01; m01 = (m01>=0.f)?m01:0.2f*m01;
    float m10 = x1x + xrv.x + em10; m10 = (m10>=0.f)?m10:0.2f*m10;
    float m11 = x1y + xrv.y + em11; m11 = (m11>=0.f)?m11:0.2f*m11;
    float m20 = x2x + xrv.x + em20; m20 = (m20>=0.f)?m20:0.2f*m20;
    float m21 = x2y + xrv.y + em21; m21 = (m21>=0.f)?m21:0.2f*m21;
    float m30 = x3x + xrv.x + em30; m30 = (m30>=0.f)?m30:0.2f*m30;
    float m31 = x3y + xrv.y + em31; m31 = (m31>=0.f)?m31:0.2f*m31;
    float v0 = fmaf(m00, at2.x, m01*at2.y);
    float v1 = fmaf(m10, at2.x, m11*at2.y);
    float v2 = fmaf(m20, at2.x, m21*at2.y);
    float v3 = fmaf(m30, at2.x, m31*at2.y);
    #pragma unroll
    for (int off = 1; off < 8; off <<= 1){
      v0 += __shfl_xor(v0, off, 8);
      v1 += __shfl_xor(v1, off, 8);
      v2 += __shfl_xor(v2, off, 8);
      v3 += __shfl_xor(v3, off, 8);
    }
    if (1 >= r) v1 = -INFINITY;
    if (2 >= r) v2 = -INFINITY;
    if (3 >= r) v3 = -INFINITY;
    float vmax = fmaxf(fmaxf(v0, v1), fmaxf(v2, v3));
    if (vmax > m){
      float sc = __expf(m - vmax);
      den *= sc; a0 *= sc; a1 *= sc; m = vmax;
    }
    float w0 = __expf(v0 - m), w1 = __expf(v1 - m);
    float w2 = __expf(v2 - m), w3 = __expf(v3 - m);
    den += (w0 + w1) + (w2 + w3);
    a0 = fmaf(w0, x0x, fmaf(w1, x1x, fmaf(w2, x2x, fmaf(w3, x3x, a0))));
    a1 = fmaf(w0, x0y, fmaf(w1, x1y, fmaf(w2, x2y, fmaf(w3, x3y, a1))));
  }
}

template<int EDM_T, int EDP_T>
__global__ void __launch_bounds__(256, 6)
k_gat_f(const uint32* __restrict__ xlu, const float2* __restrict__ xr2,
    const float* __restrict__ eaM, const float* __restrict__ eaP,
    const float* __restrict__ lwM, const float* __restrict__ atM, const float* __restrict__ biM,
    const float* __restrict__ lwP, const float* __restrict__ atP, const float* __restrict__ biP,
    const int* __restrict__ rowptr, const int* __restrict__ csr_src,
    float2* __restrict__ hout2, int NM, int NT, int EM, int edM_rt, int edP_rt)
{
  const int edM = (EDM_T > 0) ? EDM_T : edM_rt;
  const int edP = (EDP_T > 0) ? EDP_T : edP_rt;
  __shared__ float lw[24*CDIM];
  int tb = threadIdx.x;
  for (int i = tb; i < edM*CDIM; i += 256) lw[i] = lwM[i];
  for (int i = tb; i < edP*CDIM; i += 256) lw[edM*CDIM + i] = lwP[i];
  __syncthreads();
  int w = tb >> 6;
  int t = tb & 63;
  const float2* lwM2 = (const float2*)lw;
  const float2* lwP2 = (const float2*)(lw + edM*CDIM);
  float2 at2M = ((const float2*)atM)[t];
  float2 at2P = ((const float2*)atP)[t];
  float2 bb2M = ((const float2*)biM)[t];
  float2 bb2P = ((const float2*)biP)[t];
  for (int n = blockIdx.x*4 + w; n < NT; n += gridDim.x*4){
    bool mg = (n < NM);
    float2 xrv = xr2[(size_t)n*64 + t];
    int start = __builtin_amdgcn_readfirstlane(rowptr[n]);
    int end   = __builtin_amdgcn_readfirstlane(rowptr[n+1]);
    float m = -INFINITY, den = 0.f, a0 = 0.f, a1 = 0.f;
    if (mg)
      gat_edges<EDM_T>(start, end, t, 0, edM, xlu, xrv, at2M, lwM2,
                       eaM, csr_src, m, den, a0, a1);
    else
      gat_edges<EDP_T>(start, end, t, EM, edP, xlu, xrv, at2P, lwP2,
                       eaP, csr_src, m, den, a0, a1);
    float2 bb2 = mg ? bb2M : bb2P;
    float inv = 1.f/(den + 1e-16f);
    hout2[(size_t)n*64 + t] = make_float2(fmaf(a0, inv, bb2.x), fmaf(a1, inv, bb2.y));
  }
}

// ================= MFMA epilogue: x = h + elu(h@resW + resb)  (+pool on last layer) =================
__global__ void __launch_bounds__(256, 6)
k_epilogue_mfma(const float* __restrict__ hin,
    const ushort16* __restrict__ RtM, const ushort16* __restrict__ RtP,  // [128][128] bf16
    const float* __restrict__ RbM, const float* __restrict__ RbP,
    float* __restrict__ xout, int NM, int nb32M, int NP,
    const int* __restrict__ batchM, const int* __restrict__ batchP,
    float* __restrict__ pool, int dopool)
{
  __shared__ ushort16 hb[32*CDIM];   // 8 KB bf16 swizzled
  __shared__ float hf[32*CDIM];      // 16 KB f32 linear (input, then output in-place)
  int tid = threadIdx.x;
  int b = blockIdx.x;
  const ushort16* Rt; const float* Rb; const int* batch;
  int n0, nn, iobase, off;
  if (b < nb32M){ n0=b*32; nn=min(32,NM-n0); iobase=n0; Rt=RtM; Rb=RbM; batch=batchM; off=0; }
  else { n0=(b-nb32M)*32; nn=min(32,NP-n0); iobase=NM+n0; Rt=RtP; Rb=RbP; batch=batchP; off=CDIM; }
  // phase 1: stage
  for (int i = 0; i < 16; i++){
    int e = tid + i*256;
    int row = e >> 7, col = e & 127;
    float v = (row < nn) ? hin[(size_t)(iobase+row)*CDIM + col] : 0.f;
    hf[e] = v;
    int byte = (row*256 + col*2) ^ ((row & 7) << 4);
    *(ushort16*)((char*)hb + byte) = f2bf(v);
  }
  __syncthreads();
  // phase 2: MFMA
  int w = tid >> 6, t = tid & 63;
  int r16 = t & 15, kg = t >> 4;
  floatx4 acc[2][2];
  #pragma unroll
  for (int m = 0; m < 2; m++)
    #pragma unroll
    for (int nb = 0; nb < 2; nb++) acc[m][nb] = (floatx4){0.f,0.f,0.f,0.f};
  #pragma unroll
  for (int ks = 0; ks < 4; ks++){
    short8 a[2];
    #pragma unroll
    for (int m = 0; m < 2; m++){
      int row = m*16 + r16;
      int byte = (row*256 + ks*64 + kg*16) ^ ((row & 7) << 4);
      a[m] = *(const short8*)((const char*)hb + byte);
    }
    #pragma unroll
    for (int nb = 0; nb < 2; nb++){
      int col = w*32 + nb*16 + r16;
      short8 bf = *(const short8*)(Rt + (size_t)col*CDIM + ks*32 + kg*8);
      #pragma unroll
      for (int m = 0; m < 2; m++)
        acc[m][nb] = __builtin_amdgcn_mfma_f32_16x16x32_bf16(a[m], bf, acc[m][nb], 0, 0, 0);
    }
  }
  // phase 3: fold residual+elu into hf in place (unique slot owner per thread)
  #pragma unroll
  for (int nb = 0; nb < 2; nb++){
    int col = w*32 + nb*16 + r16;
    float rb = Rb[col];
    #pragma unroll
    for (int m = 0; m < 2; m++){
      #pragma unroll
      for (int reg = 0; reg < 4; reg++){
        int row = m*16 + kg*4 + reg;
        float r = acc[m][nb][reg] + rb;
        float e = (r > 0.f) ? r : expm1f(r);
        hf[row*CDIM + col] = hf[row*CDIM + col] + e;
      }
    }
  }
  __syncthreads();
  // phase 4: coalesced output
  for (int i = 0; i < 16; i++){
    int e = tid + i*256;
    int row = e >> 7, col = e & 127;
    if (row < nn){
      float val = hf[e];
      if (dopool){
        int g = batch[n0 + row];
        atomicAdd(&pool[(size_t)g*256 + off + col], val);
      } else {
        xout[(size_t)(iobase+row)*CDIM + col] = val;
      }
    }
  }
}

// ================= head =================
__global__ void k_head(const float* __restrict__ pool,
    const float* __restrict__ fc1W, const float* __restrict__ fc1b,
    const float* __restrict__ fc2W, const float* __restrict__ fc2b,
    float* __restrict__ out)
{
  __shared__ float ps[256];
  __shared__ float zs[CDIM];
  int g = blockIdx.x, t = threadIdx.x;
  ps[t]       = pool[g*256 + t];
  ps[t + 128] = pool[g*256 + 128 + t];
  __syncthreads();
  float acc = 0.f;
  for (int k = 0; k < 256; k++) acc = fmaf(ps[k], fc1W[k*CDIM + t], acc);
  acc += fc1b[t];
  float z = (acc > 0.f) ? acc : expm1f(acc);
  zs[t] = z * fc2W[t];
  __syncthreads();
  for (int s = 64; s > 0; s >>= 1){
    if (t < s) zs[t] += zs[t + s];
    __syncthreads();
  }
  if (t == 0){
    float o = zs[0] + fc2b[0];
    out[g] = 1.f / (1.f + expf(-o));
  }
}

extern "C" void kernel_launch(void* const* d_in, const int* in_sizes, int n_in,
                              void* d_out, int out_size, void* d_ws, size_t ws_size,
                              hipStream_t stream)
{
  const int NM = in_sizes[0] / CDIM, NP = in_sizes[1] / CDIM;
  const int EM = in_sizes[26] / 2,   EP = in_sizes[27] / 2;
  const int edM = in_sizes[2] / EM,  edP = in_sizes[3] / EP;
  const int NT = NM + NP, ET = EM + EP;
  const int edmax = (edM > edP) ? edM : edP;

  const int nb32M = (NM + 31)/32, nb32P = (NP + 31)/32;
  const int nbT32 = nb32M + nb32P;
  const int nbScan = (NT + 1023)/1024;

  float* Wp = (float*)d_ws;
  float* x      = Wp;                                  // NT*128 f32
  ushort16* xlh = (ushort16*)(x + (size_t)NT*CDIM);    // NT*128 bf16
  float* xr     = (float*)(xlh) + (size_t)NT*64;       // NT*128 f32 (hout aliases)
  float* pool   = xr + (size_t)NT*CDIM;                // NG*256
  int* rowptr  = (int*)(pool + (size_t)NG*256);        // NT+1
  int* deg     = rowptr + NT + 1;
  int* cursor  = deg + NT;
  int* sums    = cursor + NT;                          // nbScan+1
  int* csr_src = sums + nbScan + 1;                    // ET
  int* csr_eid = csr_src + ET;                         // ET
  float* ea_csr = (float*)(csr_eid + ET);              // EM*edM + EP*edP
  size_t ea_elems = (size_t)EM*edM + (size_t)EP*edP;
  ushort16* WtAll = (ushort16*)(ea_csr + ea_elems);    // 6*256*128 bf16
  ushort16* resWt = WtAll + (size_t)6*256*CDIM;        // 6*128*128 bf16

  size_t need = ((size_t)NT*CDIM + (size_t)NT*64 + (size_t)NT*CDIM + (size_t)NG*256)*4
              + ((size_t)3*NT + 1 + nbScan + 1 + (size_t)2*ET)*4
              + ea_elems*4
              + ((size_t)6*256*CDIM + (size_t)6*CDIM*CDIM)*2;
  if (ws_size < need) return;

  const float* xM0    = (const float*)d_in[0];
  const float* xP0    = (const float*)d_in[1];
  const float* eattrM = (const float*)d_in[2];
  const float* eattrP = (const float*)d_in[3];
  const int* eiM = (const int*)d_in[26];
  const int* eiP = (const int*)d_in[27];
  const int* batchM = (const int*)d_in[28];
  const int* batchP = (const int*)d_in[29];
  const int* srcM = eiM, *dstM = eiM + EM;
  const int* srcP = eiP, *dstP = eiP + EP;

  hipMemsetAsync(pool, 0, (size_t)NG*256*sizeof(float), stream);
  hipMemsetAsync(deg, 0, (size_t)NT*sizeof(int), stream);

  // ---- weight prep (once) ----
  {
    const int tot = 6*(256*CDIM + CDIM*CDIM);
    k_prep_w<<<(tot + 255)/256, 256, 0, stream>>>(
        (const float*)d_in[4], (const float*)d_in[6], (const float*)d_in[11],
        (const float*)d_in[13], (const float*)d_in[15], (const float*)d_in[20],
        WtAll, resWt);
  }

  // ---- unified CSR build ----
  k_count_f<<<(ET + 255)/256, 256, 0, stream>>>(dstM, dstP, deg, EM, ET, NM);
  k_scan1<<<nbScan, 1024, 0, stream>>>(deg, rowptr, sums, NT);
  k_scan2<<<1, 1024, 0, stream>>>(sums, nbScan);
  k_scan3<<<(NT + 255)/256, 256, 0, stream>>>(rowptr, cursor, sums, NT, nbScan);
  k_scatter_f<<<(ET + 255)/256, 256, 0, stream>>>(srcM, srcP, dstM, dstP, cursor,
                                                  csr_src, csr_eid, EM, ET, NM);
  k_reorder_f<<<((size_t)ET*edmax + 255)/256, 256, 0, stream>>>(
      eattrM, eattrP, csr_eid, ea_csr, EM, ET, edM, edP, edmax);
  const float* eaM_use = ea_csr;
  const float* eaP_use = ea_csr + (size_t)EM*edM;

  int gatBlocks = (NT + 3)/4;
  if (gatBlocks > 4096) gatBlocks = 4096;   // finer work granularity -> better tail balance

  auto runGat = [&](int l){
    const float* WeM = (const float*)d_in[8]  + (size_t)l*edM*CDIM;
    const float* atM = (const float*)d_in[9]  + (size_t)l*CDIM;
    const float* biM = (const float*)d_in[10] + (size_t)l*CDIM;
    const float* WeP = (const float*)d_in[17] + (size_t)l*edP*CDIM;
    const float* atP = (const float*)d_in[18] + (size_t)l*CDIM;
    const float* biP = (const float*)d_in[19] + (size_t)l*CDIM;
    if (edM == 8 && edP == 12)
      k_gat_f<8,12><<<gatBlocks, 256, 0, stream>>>((const uint32*)xlh, (const float2*)xr,
          eaM_use, eaP_use, WeM, atM, biM, WeP, atP, biP,
          rowptr, csr_src, (float2*)xr, NM, NT, EM, edM, edP);
    else
      k_gat_f<0,0><<<gatBlocks, 256, 0, stream>>>((const uint32*)xlh, (const float2*)xr,
          eaM_use, eaP_use, WeM, atM, biM, WeP, atP, biP,
          rowptr, csr_src, (float2*)xr, NM, NT, EM, edM, edP);
  };

  for (int l = 0; l < 3; l++){
    const float* blM = (const float*)d_in[5]  + (size_t)l*CDIM;
    const float* brM = (const float*)d_in[7]  + (size_t)l*CDIM;
    const float* RbM = (const float*)d_in[12] + (size_t)l*CDIM;
    const float* blP = (const float*)d_in[14] + (size_t)l*CDIM;
    const float* brP = (const float*)d_in[16] + (size_t)l*CDIM;
    const float* RbP = (const float*)d_in[21] + (size_t)l*CDIM;

    const ushort16* WtM_l = WtAll + ((size_t)(0*3 + l))*256*CDIM;
    const ushort16* WtP_l = WtAll + ((size_t)(1*3 + l))*256*CDIM;
    const ushort16* RtM_l = resWt + ((size_t)(0*3 + l))*CDIM*CDIM;
    const ushort16* RtP_l = resWt + ((size_t)(1*3 + l))*CDIM*CDIM;

    const float* xMin = (l == 0) ? xM0 : x;
    const float* xPin = (l == 0) ? xP0 : x + (size_t)NM*CDIM;

    k_transform_mfma<<<nbT32, 256, 0, stream>>>(xMin, xPin, WtM_l, WtP_l,
        blM, brM, blP, brP, xlh, xr, NM, nb32M, NP);

    runGat(l);

    k_epilogue_mfma<<<nbT32, 256, 0, stream>>>(xr, RtM_l, RtP_l, RbM, RbP, x,
        NM, nb32M, NP, batchM, batchP, pool, (l == 2) ? 1 : 0);
  }

  const float* fc1W = (const float*)d_in[22];
  const float* fc1b = (const float*)d_in[23];
  const float* fc2W = (const float*)d_in[24];
  const float* fc2b = (const float*)d_in[25];
  k_head<<<NG, 128, 0, stream>>>(pool, fc1W, fc1b, fc2W, fc2b, (float*)d_out);
}

// Round 15
// 617.058 us; speedup vs baseline: 1.1370x; 1.0267x over previous
//
#include <hip/hip_runtime.h>
#include <hip/hip_bf16.h>

#define CDIM 128
#define NG 128
typedef unsigned int uint32;
typedef unsigned short ushort16;
typedef __attribute__((ext_vector_type(8))) short short8;
typedef __attribute__((ext_vector_type(4))) float floatx4;

__device__ __forceinline__ ushort16 f2bf(float f){
  uint32 u = __float_as_uint(f);
  u = (u + 0x7fffu + ((u >> 16) & 1u)) >> 16;   // RNE
  return (ushort16)u;
}

// ================= CSR build (unified graph: mg nodes [0,NM), pg nodes [NM,NT)) =================
__global__ void k_count_f(const int* __restrict__ dstM, const int* __restrict__ dstP,
                          int* __restrict__ deg, int EM, int ET, int NM){
  int e = blockIdx.x*blockDim.x + threadIdx.x;
  if (e < ET){
    int d = (e < EM) ? dstM[e] : dstP[e-EM] + NM;
    atomicAdd(&deg[d], 1);
  }
}

__global__ void k_scan1(const int* __restrict__ deg, int* __restrict__ rowptr,
                        int* __restrict__ sums, int N){
  __shared__ int tmp[1024];
  int b = blockIdx.x, t = threadIdx.x;
  int i = b*1024 + t;
  int v = (i < N) ? deg[i] : 0;
  tmp[t] = v; __syncthreads();
  for (int off = 1; off < 1024; off <<= 1){
    int a = (t >= off) ? tmp[t-off] : 0;
    __syncthreads();
    tmp[t] += a;
    __syncthreads();
  }
  if (i < N) rowptr[i] = tmp[t] - v;
  if (t == 1023) sums[b] = tmp[t];
}

__global__ void k_scan2(int* __restrict__ sums, int nb){
  __shared__ int tmp[1024];
  __shared__ int carry;
  int t = threadIdx.x;
  if (t == 0) carry = 0;
  __syncthreads();
  for (int base = 0; base < nb; base += 1024){
    int i = base + t;
    int v = (i < nb) ? sums[i] : 0;
    tmp[t] = v; __syncthreads();
    for (int off = 1; off < 1024; off <<= 1){
      int a = (t >= off) ? tmp[t-off] : 0;
      __syncthreads();
      tmp[t] += a;
      __syncthreads();
    }
    if (i < nb) sums[i] = carry + tmp[t] - v;
    int tot = tmp[1023];
    __syncthreads();
    if (t == 0) carry += tot;
    __syncthreads();
  }
  if (t == 0) sums[nb] = carry;
}

__global__ void k_scan3(int* __restrict__ rowptr, int* __restrict__ cursor,
                        const int* __restrict__ sums, int N, int nb){
  int i = blockIdx.x*blockDim.x + threadIdx.x;
  if (i < N){
    int r = rowptr[i] + sums[i >> 10];
    rowptr[i] = r; cursor[i] = r;
  }
  if (i == 0) rowptr[N] = sums[nb];
}

__global__ void k_scatter_f(const int* __restrict__ srcM, const int* __restrict__ srcP,
                            const int* __restrict__ dstM, const int* __restrict__ dstP,
                            int* __restrict__ cursor, int* __restrict__ csr_src,
                            int* __restrict__ csr_eid, int EM, int ET, int NM){
  int e = blockIdx.x*blockDim.x + threadIdx.x;
  if (e < ET){
    int s, d;
    if (e < EM){ s = srcM[e]; d = dstM[e]; }
    else       { s = srcP[e-EM] + NM; d = dstP[e-EM] + NM; }
    int pos = atomicAdd(&cursor[d], 1);
    csr_src[pos] = s;
    csr_eid[pos] = e;
  }
}

__global__ void k_reorder_f(const float* __restrict__ eaM, const float* __restrict__ eaP,
                            const int* __restrict__ eid, float* __restrict__ ea_csr,
                            int EM, int ET, int edM, int edP, int edmax){
  int i = blockIdx.x*blockDim.x + threadIdx.x;
  if (i >= ET*edmax) return;
  int j = i/edmax, k = i - j*edmax;
  if (j < EM){
    if (k < edM) ea_csr[(size_t)j*edM + k] = eaM[(size_t)eid[j]*edM + k];
  } else {
    if (k < edP) ea_csr[(size_t)EM*edM + (size_t)(j-EM)*edP + k]
                 = eaP[(size_t)(eid[j]-EM)*edP + k];
  }
}

// ================= weight prep: Wt[n][k] bf16 (Wl||Wr as 256 cols), resWt[n][k] bf16 =================
__global__ void k_prep_w(const float* __restrict__ linlW_M, const float* __restrict__ linrW_M,
                         const float* __restrict__ resW_M,
                         const float* __restrict__ linlW_P, const float* __restrict__ linrW_P,
                         const float* __restrict__ resW_P,
                         ushort16* __restrict__ WtAll, ushort16* __restrict__ resWt){
  const int per = 256*CDIM + CDIM*CDIM;  // 49152
  int idx = blockIdx.x*blockDim.x + threadIdx.x;
  if (idx >= 6*per) return;
  int sl = idx / per; int rem = idx - sl*per;
  int s = sl / 3, l = sl % 3;
  const float* Wl = (s ? linlW_P : linlW_M) + (size_t)l*CDIM*CDIM;
  const float* Wr = (s ? linrW_P : linrW_M) + (size_t)l*CDIM*CDIM;
  const float* Rw = (s ? resW_P  : resW_M ) + (size_t)l*CDIM*CDIM;
  if (rem < 256*CDIM){
    int k = rem >> 8, n = rem & 255;
    float v = (n < CDIM) ? Wl[k*CDIM + n] : Wr[k*CDIM + (n-CDIM)];
    WtAll[((size_t)sl*256 + n)*CDIM + k] = f2bf(v);
  } else {
    int r2 = rem - 256*CDIM;
    int k = r2 >> 7, n = r2 & 127;
    resWt[((size_t)sl*CDIM + n)*CDIM + k] = f2bf(Rw[k*CDIM + n]);
  }
}

// ================= MFMA node transform (layer 0 only) =================
__global__ void __launch_bounds__(256, 4)
k_transform_mfma(const float* __restrict__ xM, const float* __restrict__ xP,
    const ushort16* __restrict__ WtM, const ushort16* __restrict__ WtP,
    const float* __restrict__ blM, const float* __restrict__ brM,
    const float* __restrict__ blP, const float* __restrict__ brP,
    ushort16* __restrict__ xlh, float* __restrict__ xr,
    int NM, int nb32M, int NP)
{
  __shared__ ushort16 xs[32*CDIM];
  __shared__ float   xro[32*CDIM];
  int tid = threadIdx.x;
  int b = blockIdx.x;
  const float* xin; const ushort16* Wt; const float *bl, *br;
  int n0, nn, outbase;
  if (b < nb32M){ xin=xM; n0=b*32; nn=min(32,NM-n0); outbase=n0; Wt=WtM; bl=blM; br=brM; }
  else { xin=xP; n0=(b-nb32M)*32; nn=min(32,NP-n0); outbase=NM+n0; Wt=WtP; bl=blP; br=brP; }
  for (int i = 0; i < 16; i++){
    int e = tid + i*256;
    int row = e >> 7, col = e & 127;
    float v = (row < nn) ? xin[(size_t)(n0+row)*CDIM + col] : 0.f;
    int byte = (row*256 + col*2) ^ ((row & 7) << 4);
    *(ushort16*)((char*)xs + byte) = f2bf(v);
  }
  __syncthreads();
  int w = tid >> 6, t = tid & 63;
  int r16 = t & 15, kg = t >> 4;
  floatx4 acc[2][4];
  #pragma unroll
  for (int m = 0; m < 2; m++)
    #pragma unroll
    for (int nb = 0; nb < 4; nb++) acc[m][nb] = (floatx4){0.f,0.f,0.f,0.f};
  #pragma unroll
  for (int ks = 0; ks < 4; ks++){
    short8 a[2];
    #pragma unroll
    for (int m = 0; m < 2; m++){
      int row = m*16 + r16;
      int byte = (row*256 + ks*64 + kg*16) ^ ((row & 7) << 4);
      a[m] = *(const short8*)((const char*)xs + byte);
    }
    #pragma unroll
    for (int nb = 0; nb < 4; nb++){
      int col = w*64 + nb*16 + r16;
      short8 bf = *(const short8*)(Wt + (size_t)col*CDIM + ks*32 + kg*8);
      #pragma unroll
      for (int m = 0; m < 2; m++)
        acc[m][nb] = __builtin_amdgcn_mfma_f32_16x16x32_bf16(a[m], bf, acc[m][nb], 0, 0, 0);
    }
  }
  __syncthreads();
  #pragma unroll
  for (int nb = 0; nb < 4; nb++){
    int col = w*64 + nb*16 + r16;
    float bias = (col < CDIM) ? bl[col] : br[col - CDIM];
    #pragma unroll
    for (int m = 0; m < 2; m++){
      #pragma unroll
      for (int reg = 0; reg < 4; reg++){
        int row = m*16 + kg*4 + reg;
        float v = acc[m][nb][reg] + bias;
        if (col < CDIM) xs[row*CDIM + col] = f2bf(v);
        else            xro[row*CDIM + (col - CDIM)] = v;
      }
    }
  }
  __syncthreads();
  for (int i = 0; i < 16; i++){
    int e = tid + i*256;
    int row = e >> 7, col = e & 127;
    if (row < nn){
      xlh[(size_t)(outbase+row)*CDIM + col] = xs[e];
      xr [(size_t)(outbase+row)*CDIM + col] = xro[e];
    }
  }
}

// ================= fused epilogue(l) + transform(l+1): h -> x (LDS only) -> xl,xr =================
__global__ void __launch_bounds__(256, 4)
k_fused_et(const float* __restrict__ hin,
    const ushort16* __restrict__ RtM, const ushort16* __restrict__ RtP,
    const float* __restrict__ RbM, const float* __restrict__ RbP,
    const ushort16* __restrict__ WtM, const ushort16* __restrict__ WtP,
    const float* __restrict__ blM, const float* __restrict__ brM,
    const float* __restrict__ blP, const float* __restrict__ brP,
    ushort16* __restrict__ xlh, float* __restrict__ xr,
    int NM, int nb32M, int NP)
{
  __shared__ ushort16 ab[32*CDIM];   // A-operand (h, then x), swizzled bf16; finally xl linear
  __shared__ float    hf[32*CDIM];   // h f32, then x f32, finally xr staging
  int tid = threadIdx.x;
  int b = blockIdx.x;
  const ushort16 *Rt, *Wt; const float *Rb, *bl, *br;
  int n0, nn, iobase;
  if (b < nb32M){ n0=b*32; nn=min(32,NM-n0); iobase=n0;
    Rt=RtM; Rb=RbM; Wt=WtM; bl=blM; br=brM; }
  else { n0=(b-nb32M)*32; nn=min(32,NP-n0); iobase=NM+n0;
    Rt=RtP; Rb=RbP; Wt=WtP; bl=blP; br=brP; }
  // phase 1: stage h
  for (int i = 0; i < 16; i++){
    int e = tid + i*256;
    int row = e >> 7, col = e & 127;
    float v = (row < nn) ? hin[(size_t)(iobase+row)*CDIM + col] : 0.f;
    hf[e] = v;
    int byte = (row*256 + col*2) ^ ((row & 7) << 4);
    *(ushort16*)((char*)ab + byte) = f2bf(v);
  }
  __syncthreads();
  int w = tid >> 6, t = tid & 63;
  int r16 = t & 15, kg = t >> 4;
  // phase 2: GEMM1 acc1 = h @ Rt  (N=128)
  floatx4 acc1[2][2];
  #pragma unroll
  for (int m = 0; m < 2; m++)
    #pragma unroll
    for (int nb = 0; nb < 2; nb++) acc1[m][nb] = (floatx4){0.f,0.f,0.f,0.f};
  #pragma unroll
  for (int ks = 0; ks < 4; ks++){
    short8 a[2];
    #pragma unroll
    for (int m = 0; m < 2; m++){
      int row = m*16 + r16;
      int byte = (row*256 + ks*64 + kg*16) ^ ((row & 7) << 4);
      a[m] = *(const short8*)((const char*)ab + byte);
    }
    #pragma unroll
    for (int nb = 0; nb < 2; nb++){
      int col = w*32 + nb*16 + r16;
      short8 bf = *(const short8*)(Rt + (size_t)col*CDIM + ks*32 + kg*8);
      #pragma unroll
      for (int m = 0; m < 2; m++)
        acc1[m][nb] = __builtin_amdgcn_mfma_f32_16x16x32_bf16(a[m], bf, acc1[m][nb], 0, 0, 0);
    }
  }
  __syncthreads();   // all reads of ab(h) done
  // phase 3: x = h + elu(acc1 + Rb) -> hf (in place) + ab (swizzled bf16)
  #pragma unroll
  for (int nb = 0; nb < 2; nb++){
    int col = w*32 + nb*16 + r16;
    float rb = Rb[col];
    #pragma unroll
    for (int m = 0; m < 2; m++){
      #pragma unroll
      for (int reg = 0; reg < 4; reg++){
        int row = m*16 + kg*4 + reg;
        float r = acc1[m][nb][reg] + rb;
        float e = (r > 0.f) ? r : expm1f(r);
        float xv = hf[row*CDIM + col] + e;
        hf[row*CDIM + col] = xv;
        int byte = (row*256 + col*2) ^ ((row & 7) << 4);
        *(ushort16*)((char*)ab + byte) = f2bf(xv);
      }
    }
  }
  __syncthreads();
  // phase 4: GEMM2 acc2 = x @ Wt  (N=256)
  floatx4 acc2[2][4];
  #pragma unroll
  for (int m = 0; m < 2; m++)
    #pragma unroll
    for (int nb = 0; nb < 4; nb++) acc2[m][nb] = (floatx4){0.f,0.f,0.f,0.f};
  #pragma unroll
  for (int ks = 0; ks < 4; ks++){
    short8 a[2];
    #pragma unroll
    for (int m = 0; m < 2; m++){
      int row = m*16 + r16;
      int byte = (row*256 + ks*64 + kg*16) ^ ((row & 7) << 4);
      a[m] = *(const short8*)((const char*)ab + byte);
    }
    #pragma unroll
    for (int nb = 0; nb < 4; nb++){
      int col = w*64 + nb*16 + r16;
      short8 bf = *(const short8*)(Wt + (size_t)col*CDIM + ks*32 + kg*8);
      #pragma unroll
      for (int m = 0; m < 2; m++)
        acc2[m][nb] = __builtin_amdgcn_mfma_f32_16x16x32_bf16(a[m], bf, acc2[m][nb], 0, 0, 0);
    }
  }
  __syncthreads();   // all reads of ab(x) done
  // phase 5: scatter xl->ab (linear bf16), xr->hf (linear f32)
  #pragma unroll
  for (int nb = 0; nb < 4; nb++){
    int col = w*64 + nb*16 + r16;
    float bias = (col < CDIM) ? bl[col] : br[col - CDIM];
    #pragma unroll
    for (int m = 0; m < 2; m++){
      #pragma unroll
      for (int reg = 0; reg < 4; reg++){
        int row = m*16 + kg*4 + reg;
        float v = acc2[m][nb][reg] + bias;
        if (col < CDIM) ab[row*CDIM + col] = f2bf(v);
        else            hf[row*CDIM + (col - CDIM)] = v;
      }
    }
  }
  __syncthreads();
  // phase 6: coalesced writes
  for (int i = 0; i < 16; i++){
    int e = tid + i*256;
    int row = e >> 7, col = e & 127;
    if (row < nn){
      xlh[(size_t)(iobase+row)*CDIM + col] = ab[e];
      xr [(size_t)(iobase+row)*CDIM + col] = hf[e];
    }
  }
}

// ================= fused GAT aggregation (round-14 structure, unchanged) =================
template<int ED>
__device__ __forceinline__ void gat_edges(
    int start, int end, int t, int j0, int ed_rt,
    const uint32* __restrict__ xlu, float2 xrv, float2 at2,
    const float2* __restrict__ lw2,
    const float* __restrict__ ea, const int* __restrict__ csr_src,
    float& m, float& den, float& a0, float& a1)
{
  const int ed = (ED > 0) ? ED : ed_rt;
  for (int j = start; j < end; j += 4){
    const int r = end - j;
    int jj1 = (1 < r) ? j+1 : j;
    int jj2 = (2 < r) ? j+2 : j;
    int jj3 = (3 < r) ? j+3 : j;
    int s0 = __builtin_amdgcn_readfirstlane(csr_src[j]);
    int s1 = __builtin_amdgcn_readfirstlane(csr_src[jj1]);
    int s2 = __builtin_amdgcn_readfirstlane(csr_src[jj2]);
    int s3 = __builtin_amdgcn_readfirstlane(csr_src[jj3]);
    int e0 = __builtin_amdgcn_readfirstlane(j   - j0);
    int e1 = __builtin_amdgcn_readfirstlane(jj1 - j0);
    int e2 = __builtin_amdgcn_readfirstlane(jj2 - j0);
    int e3 = __builtin_amdgcn_readfirstlane(jj3 - j0);
    const float* p0 = ea + (size_t)e0*ed;
    const float* p1 = ea + (size_t)e1*ed;
    const float* p2 = ea + (size_t)e2*ed;
    const float* p3 = ea + (size_t)e3*ed;
    uint32 u0 = xlu[(size_t)s0*64 + t];
    uint32 u1 = xlu[(size_t)s1*64 + t];
    uint32 u2 = xlu[(size_t)s2*64 + t];
    uint32 u3 = xlu[(size_t)s3*64 + t];
    float x0x = __uint_as_float(u0 << 16), x0y = __uint_as_float(u0 & 0xffff0000u);
    float x1x = __uint_as_float(u1 << 16), x1y = __uint_as_float(u1 & 0xffff0000u);
    float x2x = __uint_as_float(u2 << 16), x2y = __uint_as_float(u2 & 0xffff0000u);
    float x3x = __uint_as_float(u3 << 16), x3y = __uint_as_float(u3 & 0xffff0000u);
    float em00=0.f, em01=0.f, em10=0.f, em11=0.f;
    float em20=0.f, em21=0.f, em30=0.f, em31=0.f;
    #pragma unroll 4
    for (int k = 0; k < ed; k++){
      float2 lwv = lw2[k*64 + t];
      float a = p0[k], bq = p1[k], c = p2[k], d = p3[k];
      em00 = fmaf(a,  lwv.x, em00); em01 = fmaf(a,  lwv.y, em01);
      em10 = fmaf(bq, lwv.x, em10); em11 = fmaf(bq, lwv.y, em11);
      em20 = fmaf(c,  lwv.x, em20); em21 = fmaf(c,  lwv.y, em21);
      em30 = fmaf(d,  lwv.x, em30); em31 = fmaf(d,  lwv.y, em31);
    }
    float m00 = x0x + xrv.x + em00; m00 = (m00>=0.f)?m00:0.2f*m00;
    float m01 = x0y + xrv.y + em01; m01 = (m01>=0.f)?m01:0.2f*m01;
    float m10 = x1x + xrv.x + em10; m10 = (m10>=0.f)?m10:0.2f*m10;
    float m11 = x1y + xrv.y + em11; m11 = (m11>=0.f)?m11:0.2f*m11;
    float m20 = x2x + xrv.x + em20; m20 = (m20>=0.f)?m20:0.2f*m20;
    float m21 = x2y + xrv.y + em21; m21 = (m21>=0.f)?m21:0.2f*m21;
    float m30 = x3x + xrv.x + em30; m30 = (m30>=0.f)?m30:0.2f*m30;
    float m31 = x3y + xrv.y + em31; m31 = (m31>=0.f)?m31:0.2f*m31;
    float v0 = fmaf(m00, at2.x, m01*at2.y);
    float v1 = fmaf(m10, at2.x, m11*at2.y);
    float v2 = fmaf(m20, at2.x, m21*at2.y);
    float v3 = fmaf(m30, at2.x, m31*at2.y);
    #pragma unroll
    for (int off = 1; off < 8; off <<= 1){
      v0 += __shfl_xor(v0, off, 8);
      v1 += __shfl_xor(v1, off, 8);
      v2 += __shfl_xor(v2, off, 8);
      v3 += __shfl_xor(v3, off, 8);
    }
    if (1 >= r) v1 = -INFINITY;
    if (2 >= r) v2 = -INFINITY;
    if (3 >= r) v3 = -INFINITY;
    float vmax = fmaxf(fmaxf(v0, v1), fmaxf(v2, v3));
    if (vmax > m){
      float sc = __expf(m - vmax);
      den *= sc; a0 *= sc; a1 *= sc; m = vmax;
    }
    float w0 = __expf(v0 - m), w1 = __expf(v1 - m);
    float w2 = __expf(v2 - m), w3 = __expf(v3 - m);
    den += (w0 + w1) + (w2 + w3);
    a0 = fmaf(w0, x0x, fmaf(w1, x1x, fmaf(w2, x2x, fmaf(w3, x3x, a0))));
    a1 = fmaf(w0, x0y, fmaf(w1, x1y, fmaf(w2, x2y, fmaf(w3, x3y, a1))));
  }
}

template<int EDM_T, int EDP_T>
__global__ void __launch_bounds__(256, 6)
k_gat_f(const uint32* __restrict__ xlu, const float2* __restrict__ xr2,
    const float* __restrict__ eaM, const float* __restrict__ eaP,
    const float* __restrict__ lwM, const float* __restrict__ atM, const float* __restrict__ biM,
    const float* __restrict__ lwP, const float* __restrict__ atP, const float* __restrict__ biP,
    const int* __restrict__ rowptr, const int* __restrict__ csr_src,
    float2* __restrict__ hout2, int NM, int NT, int EM, int edM_rt, int edP_rt)
{
  const int edM = (EDM_T > 0) ? EDM_T : edM_rt;
  const int edP = (EDP_T > 0) ? EDP_T : edP_rt;
  __shared__ float lw[24*CDIM];
  int tb = threadIdx.x;
  for (int i = tb; i < edM*CDIM; i += 256) lw[i] = lwM[i];
  for (int i = tb; i < edP*CDIM; i += 256) lw[edM*CDIM + i] = lwP[i];
  __syncthreads();
  int w = tb >> 6;
  int t = tb & 63;
  const float2* lwM2 = (const float2*)lw;
  const float2* lwP2 = (const float2*)(lw + edM*CDIM);
  float2 at2M = ((const float2*)atM)[t];
  float2 at2P = ((const float2*)atP)[t];
  float2 bb2M = ((const float2*)biM)[t];
  float2 bb2P = ((const float2*)biP)[t];
  for (int n = blockIdx.x*4 + w; n < NT; n += gridDim.x*4){
    bool mg = (n < NM);
    float2 xrv = xr2[(size_t)n*64 + t];
    int start = __builtin_amdgcn_readfirstlane(rowptr[n]);
    int end   = __builtin_amdgcn_readfirstlane(rowptr[n+1]);
    float m = -INFINITY, den = 0.f, a0 = 0.f, a1 = 0.f;
    if (mg)
      gat_edges<EDM_T>(start, end, t, 0, edM, xlu, xrv, at2M, lwM2,
                       eaM, csr_src, m, den, a0, a1);
    else
      gat_edges<EDP_T>(start, end, t, EM, edP, xlu, xrv, at2P, lwP2,
                       eaP, csr_src, m, den, a0, a1);
    float2 bb2 = mg ? bb2M : bb2P;
    float inv = 1.f/(den + 1e-16f);
    hout2[(size_t)n*64 + t] = make_float2(fmaf(a0, inv, bb2.x), fmaf(a1, inv, bb2.y));
  }
}

// ================= MFMA epilogue (layer 2: residual + pool) =================
__global__ void __launch_bounds__(256, 4)
k_epilogue_mfma(const float* __restrict__ hin,
    const ushort16* __restrict__ RtM, const ushort16* __restrict__ RtP,
    const float* __restrict__ RbM, const float* __restrict__ RbP,
    int NM, int nb32M, int NP,
    const int* __restrict__ batchM, const int* __restrict__ batchP,
    float* __restrict__ pool)
{
  __shared__ ushort16 hb[32*CDIM];
  __shared__ float hf[32*CDIM];
  int tid = threadIdx.x;
  int b = blockIdx.x;
  const ushort16* Rt; const float* Rb; const int* batch;
  int n0, nn, iobase, off;
  if (b < nb32M){ n0=b*32; nn=min(32,NM-n0); iobase=n0; Rt=RtM; Rb=RbM; batch=batchM; off=0; }
  else { n0=(b-nb32M)*32; nn=min(32,NP-n0); iobase=NM+n0; Rt=RtP; Rb=RbP; batch=batchP; off=CDIM; }
  for (int i = 0; i < 16; i++){
    int e = tid + i*256;
    int row = e >> 7, col = e & 127;
    float v = (row < nn) ? hin[(size_t)(iobase+row)*CDIM + col] : 0.f;
    hf[e] = v;
    int byte = (row*256 + col*2) ^ ((row & 7) << 4);
    *(ushort16*)((char*)hb + byte) = f2bf(v);
  }
  __syncthreads();
  int w = tid >> 6, t = tid & 63;
  int r16 = t & 15, kg = t >> 4;
  floatx4 acc[2][2];
  #pragma unroll
  for (int m = 0; m < 2; m++)
    #pragma unroll
    for (int nb = 0; nb < 2; nb++) acc[m][nb] = (floatx4){0.f,0.f,0.f,0.f};
  #pragma unroll
  for (int ks = 0; ks < 4; ks++){
    short8 a[2];
    #pragma unroll
    for (int m = 0; m < 2; m++){
      int row = m*16 + r16;
      int byte = (row*256 + ks*64 + kg*16) ^ ((row & 7) << 4);
      a[m] = *(const short8*)((const char*)hb + byte);
    }
    #pragma unroll
    for (int nb = 0; nb < 2; nb++){
      int col = w*32 + nb*16 + r16;
      short8 bf = *(const short8*)(Rt + (size_t)col*CDIM + ks*32 + kg*8);
      #pragma unroll
      for (int m = 0; m < 2; m++)
        acc[m][nb] = __builtin_amdgcn_mfma_f32_16x16x32_bf16(a[m], bf, acc[m][nb], 0, 0, 0);
    }
  }
  #pragma unroll
  for (int nb = 0; nb < 2; nb++){
    int col = w*32 + nb*16 + r16;
    float rb = Rb[col];
    #pragma unroll
    for (int m = 0; m < 2; m++){
      #pragma unroll
      for (int reg = 0; reg < 4; reg++){
        int row = m*16 + kg*4 + reg;
        float r = acc[m][nb][reg] + rb;
        float e = (r > 0.f) ? r : expm1f(r);
        hf[row*CDIM + col] = hf[row*CDIM + col] + e;
      }
    }
  }
  __syncthreads();
  for (int i = 0; i < 16; i++){
    int e = tid + i*256;
    int row = e >> 7, col = e & 127;
    if (row < nn){
      int g = batch[n0 + row];
      atomicAdd(&pool[(size_t)g*256 + off + col], hf[e]);
    }
  }
}

// ================= head =================
__global__ void k_head(const float* __restrict__ pool,
    const float* __restrict__ fc1W, const float* __restrict__ fc1b,
    const float* __restrict__ fc2W, const float* __restrict__ fc2b,
    float* __restrict__ out)
{
  __shared__ float ps[256];
  __shared__ float zs[CDIM];
  int g = blockIdx.x, t = threadIdx.x;
  ps[t]       = pool[g*256 + t];
  ps[t + 128] = pool[g*256 + 128 + t];
  __syncthreads();
  float acc = 0.f;
  for (int k = 0; k < 256; k++) acc = fmaf(ps[k], fc1W[k*CDIM + t], acc);
  acc += fc1b[t];
  float z = (acc > 0.f) ? acc : expm1f(acc);
  zs[t] = z * fc2W[t];
  __syncthreads();
  for (int s = 64; s > 0; s >>= 1){
    if (t < s) zs[t] += zs[t + s];
    __syncthreads();
  }
  if (t == 0){
    float o = zs[0] + fc2b[0];
    out[g] = 1.f / (1.f + expf(-o));
  }
}

extern "C" void kernel_launch(void* const* d_in, const int* in_sizes, int n_in,
                              void* d_out, int out_size, void* d_ws, size_t ws_size,
                              hipStream_t stream)
{
  const int NM = in_sizes[0] / CDIM, NP = in_sizes[1] / CDIM;
  const int EM = in_sizes[26] / 2,   EP = in_sizes[27] / 2;
  const int edM = in_sizes[2] / EM,  edP = in_sizes[3] / EP;
  const int NT = NM + NP, ET = EM + EP;
  const int edmax = (edM > edP) ? edM : edP;

  const int nb32M = (NM + 31)/32, nb32P = (NP + 31)/32;
  const int nbT32 = nb32M + nb32P;
  const int nbScan = (NT + 1023)/1024;

  float* Wp = (float*)d_ws;
  float* x      = Wp;                                  // NT*128 f32 (layout keeper)
  ushort16* xlh = (ushort16*)(x + (size_t)NT*CDIM);    // NT*128 bf16
  float* xr     = (float*)(xlh) + (size_t)NT*64;       // NT*128 f32 (hout aliases)
  float* pool   = xr + (size_t)NT*CDIM;                // NG*256
  int* rowptr  = (int*)(pool + (size_t)NG*256);        // NT+1
  int* deg     = rowptr + NT + 1;
  int* cursor  = deg + NT;
  int* sums    = cursor + NT;                          // nbScan+1
  int* csr_src = sums + nbScan + 1;                    // ET
  int* csr_eid = csr_src + ET;                         // ET
  float* ea_csr = (float*)(csr_eid + ET);              // EM*edM + EP*edP
  size_t ea_elems = (size_t)EM*edM + (size_t)EP*edP;
  ushort16* WtAll = (ushort16*)(ea_csr + ea_elems);    // 6*256*128 bf16
  ushort16* resWt = WtAll + (size_t)6*256*CDIM;        // 6*128*128 bf16

  size_t need = ((size_t)NT*CDIM + (size_t)NT*64 + (size_t)NT*CDIM + (size_t)NG*256)*4
              + ((size_t)3*NT + 1 + nbScan + 1 + (size_t)2*ET)*4
              + ea_elems*4
              + ((size_t)6*256*CDIM + (size_t)6*CDIM*CDIM)*2;
  if (ws_size < need) return;

  const float* xM0    = (const float*)d_in[0];
  const float* xP0    = (const float*)d_in[1];
  const float* eattrM = (const float*)d_in[2];
  const float* eattrP = (const float*)d_in[3];
  const int* eiM = (const int*)d_in[26];
  const int* eiP = (const int*)d_in[27];
  const int* batchM = (const int*)d_in[28];
  const int* batchP = (const int*)d_in[29];
  const int* srcM = eiM, *dstM = eiM + EM;
  const int* srcP = eiP, *dstP = eiP + EP;

  hipMemsetAsync(pool, 0, (size_t)NG*256*sizeof(float), stream);
  hipMemsetAsync(deg, 0, (size_t)NT*sizeof(int), stream);

  // ---- weight prep (once) ----
  {
    const int tot = 6*(256*CDIM + CDIM*CDIM);
    k_prep_w<<<(tot + 255)/256, 256, 0, stream>>>(
        (const float*)d_in[4], (const float*)d_in[6], (const float*)d_in[11],
        (const float*)d_in[13], (const float*)d_in[15], (const float*)d_in[20],
        WtAll, resWt);
  }

  // ---- unified CSR build ----
  k_count_f<<<(ET + 255)/256, 256, 0, stream>>>(dstM, dstP, deg, EM, ET, NM);
  k_scan1<<<nbScan, 1024, 0, stream>>>(deg, rowptr, sums, NT);
  k_scan2<<<1, 1024, 0, stream>>>(sums, nbScan);
  k_scan3<<<(NT + 255)/256, 256, 0, stream>>>(rowptr, cursor, sums, NT, nbScan);
  k_scatter_f<<<(ET + 255)/256, 256, 0, stream>>>(srcM, srcP, dstM, dstP, cursor,
                                                  csr_src, csr_eid, EM, ET, NM);
  k_reorder_f<<<((size_t)ET*edmax + 255)/256, 256, 0, stream>>>(
      eattrM, eattrP, csr_eid, ea_csr, EM, ET, edM, edP, edmax);
  const float* eaM_use = ea_csr;
  const float* eaP_use = ea_csr + (size_t)EM*edM;

  int gatBlocks = (NT + 3)/4;
  if (gatBlocks > 4096) gatBlocks = 4096;

  auto runGat = [&](int l){
    const float* WeM = (const float*)d_in[8]  + (size_t)l*edM*CDIM;
    const float* atM = (const float*)d_in[9]  + (size_t)l*CDIM;
    const float* biM = (const float*)d_in[10] + (size_t)l*CDIM;
    const float* WeP = (const float*)d_in[17] + (size_t)l*edP*CDIM;
    const float* atP = (const float*)d_in[18] + (size_t)l*CDIM;
    const float* biP = (const float*)d_in[19] + (size_t)l*CDIM;
    if (edM == 8 && edP == 12)
      k_gat_f<8,12><<<gatBlocks, 256, 0, stream>>>((const uint32*)xlh, (const float2*)xr,
          eaM_use, eaP_use, WeM, atM, biM, WeP, atP, biP,
          rowptr, csr_src, (float2*)xr, NM, NT, EM, edM, edP);
    else
      k_gat_f<0,0><<<gatBlocks, 256, 0, stream>>>((const uint32*)xlh, (const float2*)xr,
          eaM_use, eaP_use, WeM, atM, biM, WeP, atP, biP,
          rowptr, csr_src, (float2*)xr, NM, NT, EM, edM, edP);
  };

  // layer 0 transform
  k_transform_mfma<<<nbT32, 256, 0, stream>>>(xM0, xP0,
      WtAll + 0*(size_t)256*CDIM, WtAll + 3*(size_t)256*CDIM,
      (const float*)d_in[5], (const float*)d_in[7],
      (const float*)d_in[14], (const float*)d_in[16],
      xlh, xr, NM, nb32M, NP);
  runGat(0);
  // boundaries: fused epilogue(l) + transform(l+1)
  for (int l = 0; l < 2; l++){
    k_fused_et<<<nbT32, 256, 0, stream>>>(xr,
        resWt + (size_t)(0*3 + l)*CDIM*CDIM, resWt + (size_t)(1*3 + l)*CDIM*CDIM,
        (const float*)d_in[12] + (size_t)l*CDIM, (const float*)d_in[21] + (size_t)l*CDIM,
        WtAll + (size_t)(0*3 + l+1)*256*CDIM, WtAll + (size_t)(1*3 + l+1)*256*CDIM,
        (const float*)d_in[5]  + (size_t)(l+1)*CDIM, (const float*)d_in[7]  + (size_t)(l+1)*CDIM,
        (const float*)d_in[14] + (size_t)(l+1)*CDIM, (const float*)d_in[16] + (size_t)(l+1)*CDIM,
        xlh, xr, NM, nb32M, NP);
    runGat(l+1);
  }
  // layer 2 epilogue + pool
  k_epilogue_mfma<<<nbT32, 256, 0, stream>>>(xr,
      resWt + (size_t)(0*3 + 2)*CDIM*CDIM, resWt + (size_t)(1*3 + 2)*CDIM*CDIM,
      (const float*)d_in[12] + (size_t)2*CDIM, (const float*)d_in[21] + (size_t)2*CDIM,
      NM, nb32M, NP, batchM, batchP, pool);

  const float* fc1W = (const float*)d_in[22];
  const float* fc1b = (const float*)d_in[23];
  const float* fc2W = (const float*)d_in[24];
  const float* fc2b = (const float*)d_in[25];
  k_head<<<NG, 128, 0, stream>>>(pool, fc1W, fc1b, fc2W, fc2b, (float*)d_out);
}